// Round 7
// baseline (2124.213 us; speedup 1.0000x reference)
//
#include <hip/hip_runtime.h>
#include <hip/hip_bf16.h>
#include <stdint.h>

#define B_ 32
#define H_ 32
#define W_ 32
#define NE 8192
#define NROWS 32768
#define K_ 256

#define MARGIN 4.0e-4f
#define CLIST_CAP (2 * 1024 * 1024)

typedef unsigned short u16;
typedef unsigned long long u64;
typedef __attribute__((ext_vector_type(8))) short short8;
typedef __attribute__((ext_vector_type(4))) float f32x4;
typedef __attribute__((ext_vector_type(4))) unsigned short us4;

__device__ __forceinline__ u16 f2bf(float f) {
    union { float f; uint32_t u; } v; v.f = f;
    uint32_t u = v.u;
    uint32_t r = (u + 0x7fffu + ((u >> 16) & 1u)) >> 16;
    return (u16)r;
}

__device__ __forceinline__ unsigned fenc(float f) {
    unsigned b = __float_as_uint(f);
    return (b & 0x80000000u) ? ~b : (b | 0x80000000u);
}
__device__ __forceinline__ float fdec(unsigned e) {
    return (e & 0x80000000u) ? __uint_as_float(e & 0x7fffffffu) : __uint_as_float(~e);
}

// exact fp32 fma chain distance (k ascending, single accumulator) — the verified r3 semantics
__device__ __forceinline__ float chain_d(const float* zp, const float* cp, float Ai) {
    float C = 0.0f;
    #pragma unroll 8
    for (int kq = 0; kq < 64; ++kq) {
        float4 zv = *(const float4*)&zp[kq * 4];
        float4 cv = *(const float4*)&cp[kq * 4];
        C = __builtin_fmaf(zv.x, cv.x, C);
        C = __builtin_fmaf(zv.y, cv.y, C);
        C = __builtin_fmaf(zv.z, cv.z, C);
        C = __builtin_fmaf(zv.w, cv.w, C);
    }
    return Ai - (C + C);
}

// ---- cb = emb @ proj^T : fp32 single-accumulator fma chain over k (BLAS replica) + bf16 copy ----
__global__ __launch_bounds__(256, 2) void k_cbchain(const float* __restrict__ emb,
                                                    const float* __restrict__ proj,
                                                    float* __restrict__ cbf,
                                                    u16* __restrict__ cbh) {
    __shared__ float pl[256][65];
    __shared__ float el[32][65];
    const int t = threadIdx.x;      // output column (proj row)
    const int jb = blockIdx.x;      // 256 blocks x 32 codes
    float acc[32];
    #pragma unroll
    for (int j = 0; j < 32; ++j) acc[j] = 0.0f;
    for (int kc = 0; kc < 4; ++kc) {
        __syncthreads();
        for (int rep = 0; rep < 64; ++rep) {
            int idx = rep * 256 + t;
            int row = idx >> 6, k = idx & 63;
            pl[row][k] = proj[(size_t)row * 256 + kc * 64 + k];
        }
        for (int rep = 0; rep < 8; ++rep) {
            int idx = rep * 256 + t;
            int row = idx >> 6, k = idx & 63;
            el[row][k] = emb[(size_t)(jb * 32 + row) * 256 + kc * 64 + k];
        }
        __syncthreads();
        for (int k = 0; k < 64; ++k) {
            float p = pl[t][k];
            #pragma unroll
            for (int j = 0; j < 32; ++j)
                acc[j] = __builtin_fmaf(el[j][k], p, acc[j]);   // k ascending, single chain
        }
    }
    for (int j = 0; j < 32; ++j) {
        size_t off = (size_t)(jb * 32 + j) * 256 + t;
        cbf[off] = acc[j];
        cbh[off] = f2bf(acc[j]);
    }
}

// ---- z[b][c][h][w] -> zrow fp32 [n][c] + zf bf16 + A[n]=||z_n||^2 ----
__global__ __launch_bounds__(256) void k_zrow(const float* __restrict__ z,
                                              float* __restrict__ zrow,
                                              u16* __restrict__ zf,
                                              float* __restrict__ Arow) {
    int bh = blockIdx.x;          // 1024 = b*32+h
    int b = bh >> 5, h = bh & 31;
    __shared__ float tile[32][257];
    __shared__ double dsum[8][32];
    int t = threadIdx.x;
    int w = t & 31, cofs = t >> 5;
    double s = 0.0;
    for (int c0 = 0; c0 < 256; c0 += 8) {
        int c = c0 + cofs;
        float v = z[(((size_t)b * 256 + c) * H_ + h) * W_ + w];
        tile[w][c] = v;
        s = fma((double)v, (double)v, s);
    }
    dsum[cofs][w] = s;
    __syncthreads();
    int n0 = (b * H_ + h) * W_;
    if (t < 32) {
        double tot = 0.0;
        #pragma unroll
        for (int q = 0; q < 8; ++q) tot += dsum[q][t];
        Arow[n0 + t] = (float)tot;   // any representable fp32 works (tie-grid invariance, r3)
    }
    for (int rep = 0; rep < 8; ++rep) {
        int uid = rep * 256 + t;
        int ww = uid >> 6, u = uid & 63;
        float4 v;
        v.x = tile[ww][u * 4 + 0];
        v.y = tile[ww][u * 4 + 1];
        v.z = tile[ww][u * 4 + 2];
        v.w = tile[ww][u * 4 + 3];
        *(float4*)&zrow[((size_t)(n0 + ww)) * 256 + u * 4] = v;
        us4 bv;
        bv.x = f2bf(v.x); bv.y = f2bf(v.y); bv.z = f2bf(v.z); bv.w = f2bf(v.w);
        *(us4*)&zf[((size_t)(n0 + ww)) * 256 + u * 4] = bv;
    }
}

// ======== LDS-free bf16 MFMA sweeps ========
// 512 blocks x 4 waves. Wave: 32 rows (wrow..wrow+31) x one j-half (4096 j, 128 tiles of 32).
// A in registers; B short8 straight from global (cbh is L1/L2-resident).
// acc[m][n][r]: row = wrow + m*16 + lg*4 + r, col j = j0 + n*16 + lr  (r4-verified mapping).

// Sweep 1: row maxes, deferred per-lane
__global__ __launch_bounds__(256) void k_rmax(const u16* __restrict__ zf,
                                              const u16* __restrict__ cbh,
                                              unsigned* __restrict__ rowmaxi) {
    const int t = threadIdx.x;
    const int wid = t >> 6, lane = t & 63;
    const int lr = lane & 15, lg = lane >> 4;
    const int wrow = blockIdx.x * 64 + (wid >> 1) * 32;
    const int jhalf = wid & 1;

    short8 a[2][8];
    #pragma unroll
    for (int m = 0; m < 2; ++m) {
        const u16* zp = zf + (size_t)(wrow + m * 16 + lr) * 256 + lg * 8;
        #pragma unroll
        for (int ks = 0; ks < 8; ++ks)
            a[m][ks] = *(const short8*)&zp[ks * 32];
    }

    const u16* pb = cbh + (size_t)(jhalf * 4096 + lr) * 256 + lg * 8;

    float rl[2][4];
    #pragma unroll
    for (int m = 0; m < 2; ++m)
        #pragma unroll
        for (int r = 0; r < 4; ++r) rl[m][r] = -3.0e38f;

    for (int jt = 0; jt < 128; ++jt) {
        const u16* pt = pb + (size_t)jt * 32 * 256;
        f32x4 acc[2][2] = {};
        #pragma unroll
        for (int ks = 0; ks < 8; ++ks) {
            short8 b0 = *(const short8*)&pt[ks * 32];
            short8 b1 = *(const short8*)&pt[ks * 32 + 16 * 256];
            acc[0][0] = __builtin_amdgcn_mfma_f32_16x16x32_bf16(a[0][ks], b0, acc[0][0], 0, 0, 0);
            acc[0][1] = __builtin_amdgcn_mfma_f32_16x16x32_bf16(a[0][ks], b1, acc[0][1], 0, 0, 0);
            acc[1][0] = __builtin_amdgcn_mfma_f32_16x16x32_bf16(a[1][ks], b0, acc[1][0], 0, 0, 0);
            acc[1][1] = __builtin_amdgcn_mfma_f32_16x16x32_bf16(a[1][ks], b1, acc[1][1], 0, 0, 0);
        }
        #pragma unroll
        for (int m = 0; m < 2; ++m)
            #pragma unroll
            for (int r = 0; r < 4; ++r)
                rl[m][r] = fmaxf(rl[m][r], fmaxf(acc[m][0][r], acc[m][1][r]));
    }
    #pragma unroll
    for (int m = 0; m < 2; ++m) {
        #pragma unroll
        for (int r = 0; r < 4; ++r) {
            float v = rl[m][r];
            #pragma unroll
            for (int mk = 1; mk < 16; mk <<= 1) v = fmaxf(v, __shfl_xor(v, mk, 64));
            if (lr == 0) atomicMax(&rowmaxi[wrow + m * 16 + lg * 4 + r], fenc(v));
        }
    }
}

// Sweep 2: bitwise-identical recompute, collect vs final threshold straight to flat list
__global__ __launch_bounds__(256) void k_collect(const u16* __restrict__ zf,
                                                 const u16* __restrict__ cbh,
                                                 const unsigned* __restrict__ rowmaxi,
                                                 unsigned* __restrict__ clist,
                                                 int* __restrict__ gcount) {
    const int t = threadIdx.x;
    const int wid = t >> 6, lane = t & 63;
    const int lr = lane & 15, lg = lane >> 4;
    const int wrow = blockIdx.x * 64 + (wid >> 1) * 32;
    const int jhalf = wid & 1;

    short8 a[2][8];
    #pragma unroll
    for (int m = 0; m < 2; ++m) {
        const u16* zp = zf + (size_t)(wrow + m * 16 + lr) * 256 + lg * 8;
        #pragma unroll
        for (int ks = 0; ks < 8; ++ks)
            a[m][ks] = *(const short8*)&zp[ks * 32];
    }
    float thr[2][4];
    #pragma unroll
    for (int m = 0; m < 2; ++m)
        #pragma unroll
        for (int r = 0; r < 4; ++r)
            thr[m][r] = fdec(rowmaxi[wrow + m * 16 + lg * 4 + r]) - MARGIN;

    const u16* pb = cbh + (size_t)(jhalf * 4096 + lr) * 256 + lg * 8;

    for (int jt = 0; jt < 128; ++jt) {
        const u16* pt = pb + (size_t)jt * 32 * 256;
        f32x4 acc[2][2] = {};
        #pragma unroll
        for (int ks = 0; ks < 8; ++ks) {
            short8 b0 = *(const short8*)&pt[ks * 32];
            short8 b1 = *(const short8*)&pt[ks * 32 + 16 * 256];
            acc[0][0] = __builtin_amdgcn_mfma_f32_16x16x32_bf16(a[0][ks], b0, acc[0][0], 0, 0, 0);
            acc[0][1] = __builtin_amdgcn_mfma_f32_16x16x32_bf16(a[0][ks], b1, acc[0][1], 0, 0, 0);
            acc[1][0] = __builtin_amdgcn_mfma_f32_16x16x32_bf16(a[1][ks], b0, acc[1][0], 0, 0, 0);
            acc[1][1] = __builtin_amdgcn_mfma_f32_16x16x32_bf16(a[1][ks], b1, acc[1][1], 0, 0, 0);
        }
        #pragma unroll
        for (int m = 0; m < 2; ++m)
            #pragma unroll
            for (int n = 0; n < 2; ++n)
                #pragma unroll
                for (int r = 0; r < 4; ++r) {
                    if (acc[m][n][r] >= thr[m][r]) {
                        int row = wrow + m * 16 + lg * 4 + r;
                        int j = jhalf * 4096 + jt * 32 + n * 16 + lr;
                        int pos = atomicAdd(gcount, 1);
                        if (pos < CLIST_CAP) clist[pos] = (unsigned)(row * NE + j);
                    }
                }
    }
}

// ---- flat exact refine: one fp32 fma chain per lane, u64 atomicMin per row ----
__global__ __launch_bounds__(256) void k_refine_flat(const float* __restrict__ zrow,
                                                     const float* __restrict__ cbf,
                                                     const float* __restrict__ Arow,
                                                     const unsigned* __restrict__ clist,
                                                     const int* __restrict__ gcount,
                                                     u64* __restrict__ rowbest) {
    int total = *gcount;
    if (total > CLIST_CAP) total = CLIST_CAP;
    for (int i = blockIdx.x * 256 + threadIdx.x; i < total; i += gridDim.x * 256) {
        unsigned e = clist[i];
        int row = e >> 13;
        int j = e & (NE - 1);
        float d = chain_d(zrow + (size_t)row * 256, cbf + (size_t)j * 256, Arow[row]);
        u64 key = ((u64)__float_as_uint(d) << 32) | (unsigned)j;   // d>0 always
        atomicMin(&rowbest[row], key);
    }
}

// ---- emit indices (never-taken exact-scan fallback makes overflow slow, not wrong) ----
__global__ __launch_bounds__(256) void k_idx(const u64* __restrict__ rowbest,
                                             const float* __restrict__ zrow,
                                             const float* __restrict__ cbf,
                                             const float* __restrict__ Arow,
                                             int* __restrict__ idxw,
                                             float* __restrict__ idxf) {
    int row = blockIdx.x * 256 + threadIdx.x;   // 128 blocks
    u64 k = rowbest[row];
    int j;
    if (k != ~0ull) {
        j = (int)(k & 0xffffffffu);
    } else {
        u64 best = ~0ull;
        for (int jj = 0; jj < NE; ++jj) {
            float d = chain_d(zrow + (size_t)row * 256, cbf + (size_t)jj * 256, Arow[row]);
            u64 key = ((u64)__float_as_uint(d) << 32) | (unsigned)jj;
            if (key < best) best = key;
        }
        j = (int)(best & 0xffffffffu);
    }
    idxw[row] = j;
    idxf[row] = (float)j;
}

// ---- zq gather + fused MSE (grid-stride, one atomic per block) ----
__global__ __launch_bounds__(256) void k_zq_mse(const float* __restrict__ z,
                                                const float* __restrict__ cbf,
                                                const int* __restrict__ idxw,
                                                float* __restrict__ zq,
                                                double* __restrict__ msesum) {
    double loc = 0.0;
    for (int i4 = blockIdx.x * 256 + threadIdx.x; i4 < NROWS * 64; i4 += 1024 * 256) {
        int id = i4 << 2;
        int w0 = (i4 & 7) * 4;
        int h = (i4 >> 3) & 31;
        int c = (i4 >> 8) & 255;
        int b = i4 >> 16;
        int nbase = (b * 32 + h) * 32 + w0;
        int4 j4 = *(const int4*)&idxw[nbase];
        float4 zv = *(const float4*)&z[id];
        float4 qv;
        qv.x = cbf[(size_t)j4.x * 256 + c];
        qv.y = cbf[(size_t)j4.y * 256 + c];
        qv.z = cbf[(size_t)j4.z * 256 + c];
        qv.w = cbf[(size_t)j4.w * 256 + c];
        *(float4*)&zq[id] = qv;
        double d0 = (double)qv.x - (double)zv.x;
        double d1 = (double)qv.y - (double)zv.y;
        double d2 = (double)qv.z - (double)zv.z;
        double d3 = (double)qv.w - (double)zv.w;
        loc += d0 * d0 + d1 * d1 + d2 * d2 + d3 * d3;
    }
    #pragma unroll
    for (int mk = 1; mk < 64; mk <<= 1) loc += __shfl_xor(loc, mk, 64);
    __shared__ double wsum[4];
    int lane = threadIdx.x & 63, wid = threadIdx.x >> 6;
    if (lane == 0) wsum[wid] = loc;
    __syncthreads();
    if (threadIdx.x == 0) {
        double tot = wsum[0] + wsum[1] + wsum[2] + wsum[3];
        atomicAdd(msesum, tot);
    }
}

// ---- finalize scalars ----
__global__ void k_final(const double* __restrict__ msesum, float* __restrict__ outs) {
    double mse = *msesum / (double)(32.0 * 256.0 * 32.0 * 32.0);
    outs[0] = (float)(1.25 * mse);   // loss
    outs[1] = (float)(0.25 * mse);   // commitment_loss
    outs[2] = (float)mse;            // codebook_loss
}

extern "C" void kernel_launch(void* const* d_in, const int* in_sizes, int n_in,
                              void* d_out, int out_size, void* d_ws, size_t ws_size,
                              hipStream_t stream) {
    const float* z    = (const float*)d_in[0];
    const float* emb  = (const float*)d_in[1];
    const float* proj = (const float*)d_in[2];
    float* out = (float*)d_out;

    char* ws = (char*)d_ws;
    size_t o = 0;
    float*    cbf     = (float*)   (ws + o); o += (size_t)NE * 256 * 4;       // 8 MB
    u16*      cbh     = (u16*)     (ws + o); o += (size_t)NE * 256 * 2;       // 4 MB
    float*    zrow    = (float*)   (ws + o); o += (size_t)NROWS * 256 * 4;    // 32 MB
    u16*      zf      = (u16*)     (ws + o); o += (size_t)NROWS * 256 * 2;    // 16 MB
    float*    Arow    = (float*)   (ws + o); o += (size_t)NROWS * 4;
    unsigned* rowmaxi = (unsigned*)(ws + o); o += (size_t)NROWS * 4;
    unsigned* clist   = (unsigned*)(ws + o); o += (size_t)CLIST_CAP * 4;      // 8 MB
    u64*      rowbest = (u64*)     (ws + o); o += (size_t)NROWS * 8;          // 256 KB
    int*      idxw    = (int*)     (ws + o); o += (size_t)NROWS * 4;
    int*      gcount  = (int*)     (ws + o); o += 64;
    double*   msesum  = (double*)  (ws + o); o += 64;
    if (o > ws_size) return;

    hipMemsetAsync(rowmaxi, 0, (size_t)NROWS * 4, stream);     // encode(-inf)
    hipMemsetAsync(rowbest, 0xFF, (size_t)NROWS * 8, stream);  // ~0ull
    hipMemsetAsync(gcount, 0, 8, stream);
    hipMemsetAsync(msesum, 0, 8, stream);

    k_cbchain<<<dim3(256),  dim3(256), 0, stream>>>(emb, proj, cbf, cbh);
    k_zrow<<<dim3(1024), dim3(256), 0, stream>>>(z, zrow, zf, Arow);
    k_rmax<<<dim3(512), dim3(256), 0, stream>>>(zf, cbh, rowmaxi);
    k_collect<<<dim3(512), dim3(256), 0, stream>>>(zf, cbh, rowmaxi, clist, gcount);
    k_refine_flat<<<dim3(1024), dim3(256), 0, stream>>>(zrow, cbf, Arow, clist, gcount, rowbest);
    k_idx<<<dim3(NROWS / 256), dim3(256), 0, stream>>>(rowbest, zrow, cbf, Arow, idxw, out + 8388611);
    k_zq_mse<<<dim3(1024), dim3(256), 0, stream>>>(z, cbf, idxw, out, msesum);
    k_final<<<dim3(1), dim3(1), 0, stream>>>(msesum, out + 8388608);
}

// Round 8
// 1407.940 us; speedup vs baseline: 1.5087x; 1.5087x over previous
//
#include <hip/hip_runtime.h>
#include <hip/hip_bf16.h>
#include <stdint.h>

#define B_ 32
#define H_ 32
#define W_ 32
#define NE 8192
#define NROWS 32768
#define K_ 256

#define BM 128
#define BN 128
#define BK 64
#define MARGIN 4.0e-4f

typedef unsigned short u16;
typedef unsigned long long u64;
typedef __attribute__((ext_vector_type(8))) short short8;
typedef __attribute__((ext_vector_type(4))) float f32x4;
typedef __attribute__((ext_vector_type(4))) unsigned short us4;

__device__ __forceinline__ u16 f2bf(float f) {
    union { float f; uint32_t u; } v; v.f = f;
    uint32_t u = v.u;
    uint32_t r = (u + 0x7fffu + ((u >> 16) & 1u)) >> 16;
    return (u16)r;
}

__device__ __forceinline__ void gload_lds16(const u16* g, u16* l) {
    __builtin_amdgcn_global_load_lds((const __attribute__((address_space(1))) void*)g,
                                     (__attribute__((address_space(3))) void*)l, 16, 0, 0);
}

// exact fp32 fma chain distance (k ascending, single accumulator) — verified r3 semantics
__device__ __forceinline__ float chain_d(const float* zp, const float* cp, float Ai) {
    float C = 0.0f;
    #pragma unroll 8
    for (int kq = 0; kq < 64; ++kq) {
        float4 zv = *(const float4*)&zp[kq * 4];
        float4 cv = *(const float4*)&cp[kq * 4];
        C = __builtin_fmaf(zv.x, cv.x, C);
        C = __builtin_fmaf(zv.y, cv.y, C);
        C = __builtin_fmaf(zv.z, cv.z, C);
        C = __builtin_fmaf(zv.w, cv.w, C);
    }
    return Ai - (C + C);
}

// ---- cb = emb @ proj^T : fp32 single-accumulator fma chain over k (BLAS replica) + bf16 copy ----
__global__ __launch_bounds__(256, 2) void k_cbchain(const float* __restrict__ emb,
                                                    const float* __restrict__ proj,
                                                    float* __restrict__ cbf,
                                                    u16* __restrict__ cbh) {
    __shared__ float pl[256][65];
    __shared__ float el[32][65];
    const int t = threadIdx.x;      // output column (proj row)
    const int jb = blockIdx.x;      // 256 blocks x 32 codes
    float acc[32];
    #pragma unroll
    for (int j = 0; j < 32; ++j) acc[j] = 0.0f;
    for (int kc = 0; kc < 4; ++kc) {
        __syncthreads();
        for (int rep = 0; rep < 64; ++rep) {
            int idx = rep * 256 + t;
            int row = idx >> 6, k = idx & 63;
            pl[row][k] = proj[(size_t)row * 256 + kc * 64 + k];
        }
        for (int rep = 0; rep < 8; ++rep) {
            int idx = rep * 256 + t;
            int row = idx >> 6, k = idx & 63;
            el[row][k] = emb[(size_t)(jb * 32 + row) * 256 + kc * 64 + k];
        }
        __syncthreads();
        for (int k = 0; k < 64; ++k) {
            float p = pl[t][k];
            #pragma unroll
            for (int j = 0; j < 32; ++j)
                acc[j] = __builtin_fmaf(el[j][k], p, acc[j]);   // k ascending, single chain
        }
    }
    for (int j = 0; j < 32; ++j) {
        size_t off = (size_t)(jb * 32 + j) * 256 + t;
        cbf[off] = acc[j];
        cbh[off] = f2bf(acc[j]);
    }
}

// ---- z[b][c][h][w] -> zrow fp32 [n][c] + zf bf16 + A[n]=||z_n||^2 ----
__global__ __launch_bounds__(256) void k_zrow(const float* __restrict__ z,
                                              float* __restrict__ zrow,
                                              u16* __restrict__ zf,
                                              float* __restrict__ Arow) {
    int bh = blockIdx.x;          // 1024 = b*32+h
    int b = bh >> 5, h = bh & 31;
    __shared__ float tile[32][257];
    __shared__ double dsum[8][32];
    int t = threadIdx.x;
    int w = t & 31, cofs = t >> 5;
    double s = 0.0;
    for (int c0 = 0; c0 < 256; c0 += 8) {
        int c = c0 + cofs;
        float v = z[(((size_t)b * 256 + c) * H_ + h) * W_ + w];
        tile[w][c] = v;
        s = fma((double)v, (double)v, s);
    }
    dsum[cofs][w] = s;
    __syncthreads();
    int n0 = (b * H_ + h) * W_;
    if (t < 32) {
        double tot = 0.0;
        #pragma unroll
        for (int q = 0; q < 8; ++q) tot += dsum[q][t];
        Arow[n0 + t] = (float)tot;   // any representable fp32 works (tie-grid invariance, r3)
    }
    for (int rep = 0; rep < 8; ++rep) {
        int uid = rep * 256 + t;
        int ww = uid >> 6, u = uid & 63;
        float4 v;
        v.x = tile[ww][u * 4 + 0];
        v.y = tile[ww][u * 4 + 1];
        v.z = tile[ww][u * 4 + 2];
        v.w = tile[ww][u * 4 + 3];
        *(float4*)&zrow[((size_t)(n0 + ww)) * 256 + u * 4] = v;
        us4 bv;
        bv.x = f2bf(v.x); bv.y = f2bf(v.y); bv.z = f2bf(v.z); bv.w = f2bf(v.w);
        *(us4*)&zf[((size_t)(n0 + ww)) * 256 + u * 4] = bv;
    }
}

// ---- ONE full bf16-MFMA GEMM (m97/LDS-staged, the r4/r5-proven structure) ----
// writes pmax[row][q]: max screen score in 64-j chunk q (q = bn*2 + wc), unique slot, no atomics
__global__ __launch_bounds__(256) void k_screenmax(const u16* __restrict__ zf,
                                                   const u16* __restrict__ cbh,
                                                   float* __restrict__ pmax) {
    __shared__ u16 As[2][BM * BK];
    __shared__ u16 Bs[2][BN * BK];
    const int bid = blockIdx.x;
    const int bn = bid & 63, bm = bid >> 6;
    const int t = threadIdx.x;
    const int wid = t >> 6, lane = t & 63;
    const int wr = wid >> 1, wc = wid & 1;
    const int lr = lane & 15, lg = lane >> 4;

    auto stage = [&](int buf, int kt) {
        const u16* gA = zf + (size_t)bm * BM * K_ + kt * BK;
        const u16* gB = cbh + (size_t)bn * BN * K_ + kt * BK;
        #pragma unroll
        for (int q = 0; q < 4; ++q) {
            int row = wid * 32 + q * 8 + (lane >> 3);
            const u16* srcA = gA + (size_t)row * K_ + (lane & 7) * 8;
            u16* dstA = &As[buf][(wid * 32 + q * 8) * BK];   // wave-uniform base
            gload_lds16(srcA, dstA);
            const u16* srcB = gB + (size_t)row * K_ + (lane & 7) * 8;
            u16* dstB = &Bs[buf][(wid * 32 + q * 8) * BK];
            gload_lds16(srcB, dstB);
        }
    };

    f32x4 acc[4][4] = {};

    auto compute = [&](int buf) {
        #pragma unroll
        for (int kk = 0; kk < BK; kk += 32) {
            short8 a[4], b[4];
            #pragma unroll
            for (int m = 0; m < 4; ++m)
                a[m] = *(const short8*)&As[buf][(wr * 64 + m * 16 + lr) * BK + kk + lg * 8];
            #pragma unroll
            for (int n = 0; n < 4; ++n)
                b[n] = *(const short8*)&Bs[buf][(wc * 64 + n * 16 + lr) * BK + kk + lg * 8];
            #pragma unroll
            for (int m = 0; m < 4; ++m)
                #pragma unroll
                for (int n = 0; n < 4; ++n)
                    acc[m][n] = __builtin_amdgcn_mfma_f32_16x16x32_bf16(a[m], b[n], acc[m][n], 0, 0, 0);
        }
    };

    stage(0, 0);
    __syncthreads();
    int cur = 0;
    #pragma unroll
    for (int kt = 0; kt < 4; ++kt) {
        if (kt < 3) stage(cur ^ 1, kt + 1);
        compute(cur);
        __syncthreads();
        cur ^= 1;
    }

    #pragma unroll
    for (int m = 0; m < 4; ++m) {
        #pragma unroll
        for (int r = 0; r < 4; ++r) {
            float v = fmaxf(fmaxf(acc[m][0][r], acc[m][1][r]),
                            fmaxf(acc[m][2][r], acc[m][3][r]));
            #pragma unroll
            for (int mk = 1; mk < 16; mk <<= 1) v = fmaxf(v, __shfl_xor(v, mk, 64));
            if (lr == 0) {
                int row = bm * BM + wr * 64 + m * 16 + lg * 4 + r;
                pmax[(size_t)row * 128 + bn * 2 + wc] = v;
            }
        }
    }
}

// ---- rowmax reduce (r2-proven) ----
__global__ __launch_bounds__(256) void k_rowmax(const float* __restrict__ pmax,
                                                float* __restrict__ rowmax) {
    int row = blockIdx.x * 4 + (threadIdx.x >> 6);
    int lane = threadIdx.x & 63;
    const float* p = pmax + (size_t)row * 128;
    float v = fmaxf(p[lane], p[lane + 64]);
    #pragma unroll
    for (int mk = 1; mk < 64; mk <<= 1) v = fmaxf(v, __shfl_xor(v, mk, 64));
    if (lane == 0) rowmax[row] = v;
}

// ---- block-scan: per row, exact-chain every j in flagged 64-j chunks; first-min-wins ----
__global__ __launch_bounds__(256) void k_blockscan(const float* __restrict__ zrow,
                                                   const float* __restrict__ cbf,
                                                   const float* __restrict__ Arow,
                                                   const float* __restrict__ pmax,
                                                   const float* __restrict__ rowmax,
                                                   int* __restrict__ idxw,
                                                   float* __restrict__ idxf) {
    __shared__ float zsh[4][256];
    const int wid = threadIdx.x >> 6, lane = threadIdx.x & 63;
    const int row = blockIdx.x * 4 + wid;      // 8192 blocks, one row per wave
    *(float4*)&zsh[wid][lane * 4] = *(const float4*)&zrow[(size_t)row * 256 + lane * 4];
    __syncthreads();

    const float Ai = Arow[row];
    const float thr = rowmax[row] - MARGIN;
    const float* p = pmax + (size_t)row * 128;
    u64 best = ~0ull;

    u64 masks[2];
    masks[0] = __ballot(p[lane] >= thr);
    masks[1] = __ballot(p[lane + 64] >= thr);

    #pragma unroll
    for (int h = 0; h < 2; ++h) {
        u64 mask = masks[h];
        while (mask) {
            int q2 = __ffsll((unsigned long long)mask) - 1;
            mask &= mask - 1;
            int q = h * 64 + q2;               // chunk covers j in [q*64, q*64+64)
            int j = q * 64 + lane;
            float d = chain_d(&zsh[wid][0], cbf + (size_t)j * 256, Ai);
            u64 key = ((u64)__float_as_uint(d) << 32) | (unsigned)j;   // d>0 always
            if (key < best) best = key;
        }
    }
    #pragma unroll
    for (int mk = 1; mk < 64; mk <<= 1) {
        u64 o = __shfl_xor(best, mk, 64);
        if (o < best) best = o;
    }
    if (lane == 0) {
        int bj = (int)(best & 0xffffffffu);
        idxw[row] = bj;
        idxf[row] = (float)bj;
    }
}

// ---- zq gather + fused MSE (grid-stride, one atomic per block) ----
__global__ __launch_bounds__(256) void k_zq_mse(const float* __restrict__ z,
                                                const float* __restrict__ cbf,
                                                const int* __restrict__ idxw,
                                                float* __restrict__ zq,
                                                double* __restrict__ msesum) {
    double loc = 0.0;
    for (int i4 = blockIdx.x * 256 + threadIdx.x; i4 < NROWS * 64; i4 += 1024 * 256) {
        int id = i4 << 2;
        int w0 = (i4 & 7) * 4;
        int h = (i4 >> 3) & 31;
        int c = (i4 >> 8) & 255;
        int b = i4 >> 16;
        int nbase = (b * 32 + h) * 32 + w0;
        int4 j4 = *(const int4*)&idxw[nbase];
        float4 zv = *(const float4*)&z[id];
        float4 qv;
        qv.x = cbf[(size_t)j4.x * 256 + c];
        qv.y = cbf[(size_t)j4.y * 256 + c];
        qv.z = cbf[(size_t)j4.z * 256 + c];
        qv.w = cbf[(size_t)j4.w * 256 + c];
        *(float4*)&zq[id] = qv;
        double d0 = (double)qv.x - (double)zv.x;
        double d1 = (double)qv.y - (double)zv.y;
        double d2 = (double)qv.z - (double)zv.z;
        double d3 = (double)qv.w - (double)zv.w;
        loc += d0 * d0 + d1 * d1 + d2 * d2 + d3 * d3;
    }
    #pragma unroll
    for (int mk = 1; mk < 64; mk <<= 1) loc += __shfl_xor(loc, mk, 64);
    __shared__ double wsum[4];
    int lane = threadIdx.x & 63, wid = threadIdx.x >> 6;
    if (lane == 0) wsum[wid] = loc;
    __syncthreads();
    if (threadIdx.x == 0) {
        double tot = wsum[0] + wsum[1] + wsum[2] + wsum[3];
        atomicAdd(msesum, tot);
    }
}

// ---- finalize scalars ----
__global__ void k_final(const double* __restrict__ msesum, float* __restrict__ outs) {
    double mse = *msesum / (double)(32.0 * 256.0 * 32.0 * 32.0);
    outs[0] = (float)(1.25 * mse);   // loss
    outs[1] = (float)(0.25 * mse);   // commitment_loss
    outs[2] = (float)mse;            // codebook_loss
}

extern "C" void kernel_launch(void* const* d_in, const int* in_sizes, int n_in,
                              void* d_out, int out_size, void* d_ws, size_t ws_size,
                              hipStream_t stream) {
    const float* z    = (const float*)d_in[0];
    const float* emb  = (const float*)d_in[1];
    const float* proj = (const float*)d_in[2];
    float* out = (float*)d_out;

    char* ws = (char*)d_ws;
    size_t o = 0;
    float*  cbf    = (float*) (ws + o); o += (size_t)NE * 256 * 4;       // 8 MB
    u16*    cbh    = (u16*)   (ws + o); o += (size_t)NE * 256 * 2;       // 4 MB
    float*  zrow   = (float*) (ws + o); o += (size_t)NROWS * 256 * 4;    // 32 MB
    u16*    zf     = (u16*)   (ws + o); o += (size_t)NROWS * 256 * 2;    // 16 MB
    float*  Arow   = (float*) (ws + o); o += (size_t)NROWS * 4;
    float*  pmax   = (float*) (ws + o); o += (size_t)NROWS * 128 * 4;    // 16 MB
    float*  rowmax = (float*) (ws + o); o += (size_t)NROWS * 4;
    int*    idxw   = (int*)   (ws + o); o += (size_t)NROWS * 4;
    double* msesum = (double*)(ws + o); o += 64;
    if (o > ws_size) return;

    hipMemsetAsync(msesum, 0, 8, stream);

    k_cbchain<<<dim3(256),  dim3(256), 0, stream>>>(emb, proj, cbf, cbh);
    k_zrow<<<dim3(1024), dim3(256), 0, stream>>>(z, zrow, zf, Arow);
    k_screenmax<<<dim3(16384), dim3(256), 0, stream>>>(zf, cbh, pmax);
    k_rowmax<<<dim3(NROWS / 4), dim3(256), 0, stream>>>(pmax, rowmax);
    k_blockscan<<<dim3(NROWS / 4), dim3(256), 0, stream>>>(zrow, cbf, Arow, pmax, rowmax, idxw, out + 8388611);
    k_zq_mse<<<dim3(1024), dim3(256), 0, stream>>>(z, cbf, idxw, out, msesum);
    k_final<<<dim3(1), dim3(1), 0, stream>>>(msesum, out + 8388608);
}

// Round 9
// 847.995 us; speedup vs baseline: 2.5050x; 1.6603x over previous
//
#include <hip/hip_runtime.h>
#include <hip/hip_bf16.h>
#include <stdint.h>

#define B_ 32
#define H_ 32
#define W_ 32
#define NE 8192
#define NROWS 32768
#define K_ 256

#define BM 128
#define BN 128
#define BK 64
#define MARGIN 4.0e-4f
#define NCHUNK 256          // 32-j chunks
#define MAXPER 1024
#define OVCAP (256 * 1024)

typedef unsigned short u16;
typedef unsigned long long u64;
typedef __attribute__((ext_vector_type(8))) short short8;
typedef __attribute__((ext_vector_type(4))) float f32x4;
typedef __attribute__((ext_vector_type(4))) unsigned short us4;

__device__ __forceinline__ u16 f2bf(float f) {
    union { float f; uint32_t u; } v; v.f = f;
    uint32_t u = v.u;
    uint32_t r = (u + 0x7fffu + ((u >> 16) & 1u)) >> 16;
    return (u16)r;
}

__device__ __forceinline__ unsigned fenc(float f) {
    unsigned b = __float_as_uint(f);
    return (b & 0x80000000u) ? ~b : (b | 0x80000000u);
}
__device__ __forceinline__ float fdec(unsigned e) {
    return (e & 0x80000000u) ? __uint_as_float(e & 0x7fffffffu) : __uint_as_float(~e);
}
// monotone u16 upper-bound encoding (round-up in fenc domain)
__device__ __forceinline__ u16 enc16ub(float f) {
    unsigned e = fenc(f);
    return (u16)((e >> 16) + ((e & 0xFFFFu) ? 1u : 0u));
}

__device__ __forceinline__ void gload_lds16(const u16* g, u16* l) {
    __builtin_amdgcn_global_load_lds((const __attribute__((address_space(1))) void*)g,
                                     (__attribute__((address_space(3))) void*)l, 16, 0, 0);
}

// exact fp32 fma chain distance (k ascending, single accumulator) — verified r3 semantics
__device__ __forceinline__ float chain_d(const float* zp, const float* cp, float Ai) {
    float C = 0.0f;
    #pragma unroll 8
    for (int kq = 0; kq < 64; ++kq) {
        float4 zv = *(const float4*)&zp[kq * 4];
        float4 cv = *(const float4*)&cp[kq * 4];
        C = __builtin_fmaf(zv.x, cv.x, C);
        C = __builtin_fmaf(zv.y, cv.y, C);
        C = __builtin_fmaf(zv.z, cv.z, C);
        C = __builtin_fmaf(zv.w, cv.w, C);
    }
    return Ai - (C + C);
}

// ---- cb = emb @ proj^T : fp32 single-accumulator fma chain over k (BLAS replica) + bf16 copy ----
__global__ __launch_bounds__(256, 2) void k_cbchain(const float* __restrict__ emb,
                                                    const float* __restrict__ proj,
                                                    float* __restrict__ cbf,
                                                    u16* __restrict__ cbh) {
    __shared__ float pl[256][65];
    __shared__ float el[32][65];
    const int t = threadIdx.x;      // output column (proj row)
    const int jb = blockIdx.x;      // 256 blocks x 32 codes
    float acc[32];
    #pragma unroll
    for (int j = 0; j < 32; ++j) acc[j] = 0.0f;
    for (int kc = 0; kc < 4; ++kc) {
        __syncthreads();
        for (int rep = 0; rep < 64; ++rep) {
            int idx = rep * 256 + t;
            int row = idx >> 6, k = idx & 63;
            pl[row][k] = proj[(size_t)row * 256 + kc * 64 + k];
        }
        for (int rep = 0; rep < 8; ++rep) {
            int idx = rep * 256 + t;
            int row = idx >> 6, k = idx & 63;
            el[row][k] = emb[(size_t)(jb * 32 + row) * 256 + kc * 64 + k];
        }
        __syncthreads();
        for (int k = 0; k < 64; ++k) {
            float p = pl[t][k];
            #pragma unroll
            for (int j = 0; j < 32; ++j)
                acc[j] = __builtin_fmaf(el[j][k], p, acc[j]);   // k ascending, single chain
        }
    }
    for (int j = 0; j < 32; ++j) {
        size_t off = (size_t)(jb * 32 + j) * 256 + t;
        cbf[off] = acc[j];
        cbh[off] = f2bf(acc[j]);
    }
}

// ---- z[b][c][h][w] -> zrow fp32 [n][c] + zf bf16 + A[n]=||z_n||^2 ----
__global__ __launch_bounds__(256) void k_zrow(const float* __restrict__ z,
                                              float* __restrict__ zrow,
                                              u16* __restrict__ zf,
                                              float* __restrict__ Arow) {
    int bh = blockIdx.x;          // 1024 = b*32+h
    int b = bh >> 5, h = bh & 31;
    __shared__ float tile[32][257];
    __shared__ double dsum[8][32];
    int t = threadIdx.x;
    int w = t & 31, cofs = t >> 5;
    double s = 0.0;
    for (int c0 = 0; c0 < 256; c0 += 8) {
        int c = c0 + cofs;
        float v = z[(((size_t)b * 256 + c) * H_ + h) * W_ + w];
        tile[w][c] = v;
        s = fma((double)v, (double)v, s);
    }
    dsum[cofs][w] = s;
    __syncthreads();
    int n0 = (b * H_ + h) * W_;
    if (t < 32) {
        double tot = 0.0;
        #pragma unroll
        for (int q = 0; q < 8; ++q) tot += dsum[q][t];
        Arow[n0 + t] = (float)tot;   // any representable fp32 works (tie-grid invariance, r3)
    }
    for (int rep = 0; rep < 8; ++rep) {
        int uid = rep * 256 + t;
        int ww = uid >> 6, u = uid & 63;
        float4 v;
        v.x = tile[ww][u * 4 + 0];
        v.y = tile[ww][u * 4 + 1];
        v.z = tile[ww][u * 4 + 2];
        v.w = tile[ww][u * 4 + 3];
        *(float4*)&zrow[((size_t)(n0 + ww)) * 256 + u * 4] = v;
        us4 bv;
        bv.x = f2bf(v.x); bv.y = f2bf(v.y); bv.z = f2bf(v.z); bv.w = f2bf(v.w);
        *(us4*)&zf[((size_t)(n0 + ww)) * 256 + u * 4] = bv;
    }
}

// ---- ONE full bf16-MFMA GEMM (m97/LDS-staged, r4/r5/r8-proven structure) ----
// epilogue: exact fp32 row max via atomicMax(fenc) + per-32-j-chunk u16 round-up maxima
__global__ __launch_bounds__(256) void k_screenmax(const u16* __restrict__ zf,
                                                   const u16* __restrict__ cbh,
                                                   unsigned* __restrict__ rowmaxi,
                                                   unsigned* __restrict__ pmax32) {
    __shared__ u16 As[2][BM * BK];
    __shared__ u16 Bs[2][BN * BK];
    const int bid = blockIdx.x;
    const int bn = bid & 63, bm = bid >> 6;
    const int t = threadIdx.x;
    const int wid = t >> 6, lane = t & 63;
    const int wr = wid >> 1, wc = wid & 1;
    const int lr = lane & 15, lg = lane >> 4;

    auto stage = [&](int buf, int kt) {
        const u16* gA = zf + (size_t)bm * BM * K_ + kt * BK;
        const u16* gB = cbh + (size_t)bn * BN * K_ + kt * BK;
        #pragma unroll
        for (int q = 0; q < 4; ++q) {
            int row = wid * 32 + q * 8 + (lane >> 3);
            const u16* srcA = gA + (size_t)row * K_ + (lane & 7) * 8;
            u16* dstA = &As[buf][(wid * 32 + q * 8) * BK];   // wave-uniform base
            gload_lds16(srcA, dstA);
            const u16* srcB = gB + (size_t)row * K_ + (lane & 7) * 8;
            u16* dstB = &Bs[buf][(wid * 32 + q * 8) * BK];
            gload_lds16(srcB, dstB);
        }
    };

    f32x4 acc[4][4] = {};

    auto compute = [&](int buf) {
        #pragma unroll
        for (int kk = 0; kk < BK; kk += 32) {
            short8 a[4], b[4];
            #pragma unroll
            for (int m = 0; m < 4; ++m)
                a[m] = *(const short8*)&As[buf][(wr * 64 + m * 16 + lr) * BK + kk + lg * 8];
            #pragma unroll
            for (int n = 0; n < 4; ++n)
                b[n] = *(const short8*)&Bs[buf][(wc * 64 + n * 16 + lr) * BK + kk + lg * 8];
            #pragma unroll
            for (int m = 0; m < 4; ++m)
                #pragma unroll
                for (int n = 0; n < 4; ++n)
                    acc[m][n] = __builtin_amdgcn_mfma_f32_16x16x32_bf16(a[m], b[n], acc[m][n], 0, 0, 0);
        }
    };

    stage(0, 0);
    __syncthreads();
    int cur = 0;
    #pragma unroll
    for (int kt = 0; kt < 4; ++kt) {
        if (kt < 3) stage(cur ^ 1, kt + 1);
        compute(cur);
        __syncthreads();
        cur ^= 1;
    }

    #pragma unroll
    for (int m = 0; m < 4; ++m) {
        #pragma unroll
        for (int r = 0; r < 4; ++r) {
            float v0 = fmaxf(acc[m][0][r], acc[m][1][r]);   // cols wc*64 + [0,32)
            float v1 = fmaxf(acc[m][2][r], acc[m][3][r]);   // cols wc*64 + [32,64)
            #pragma unroll
            for (int mk = 1; mk < 16; mk <<= 1) {
                v0 = fmaxf(v0, __shfl_xor(v0, mk, 64));
                v1 = fmaxf(v1, __shfl_xor(v1, mk, 64));
            }
            if (lr == 0) {
                int row = bm * BM + wr * 64 + m * 16 + lg * 4 + r;
                atomicMax(&rowmaxi[row], fenc(fmaxf(v0, v1)));
                unsigned pack = (unsigned)enc16ub(v0) | ((unsigned)enc16ub(v1) << 16);
                pmax32[(size_t)row * 128 + bn * 2 + wc] = pack;
            }
        }
    }
}

// ---- flag chunks >= thr into per-chunk row buckets ----
__global__ __launch_bounds__(256) void k_flag(const unsigned* __restrict__ rowmaxi,
                                              const unsigned* __restrict__ pmax32,
                                              int* __restrict__ chunkcnt,     // stride 16 (pad)
                                              int* __restrict__ chunkrows,
                                              int* __restrict__ ovcnt,
                                              unsigned* __restrict__ ovlist) {
    int row = blockIdx.x * 256 + threadIdx.x;   // 128 blocks
    float thr = fdec(rowmaxi[row]) - MARGIN;
    const unsigned* p = pmax32 + (size_t)row * 128;
    for (int q4 = 0; q4 < 32; ++q4) {
        uint4 v = *(const uint4*)&p[q4 * 4];
        unsigned ws[4] = {v.x, v.y, v.z, v.w};
        #pragma unroll
        for (int e = 0; e < 4; ++e) {
            #pragma unroll
            for (int hh = 0; hh < 2; ++hh) {
                unsigned h = (ws[e] >> (hh * 16)) & 0xFFFFu;
                if (fdec(h << 16) >= thr) {
                    int chunk = (q4 * 4 + e) * 2 + hh;
                    int slot = atomicAdd(&chunkcnt[chunk * 16], 1);
                    if (slot < MAXPER) {
                        chunkrows[chunk * MAXPER + slot] = row;
                    } else {
                        int op = atomicAdd(ovcnt, 1);
                        if (op < OVCAP) ovlist[op] = (unsigned)(row * NCHUNK + chunk);
                    }
                }
            }
        }
    }
}

// ---- refine by chunk: stage 32 codes of cbf in LDS once, reuse across bucket rows ----
__global__ __launch_bounds__(256) void k_refine_bychunk(const float* __restrict__ zrow,
                                                        const float* __restrict__ cbf,
                                                        const float* __restrict__ Arow,
                                                        const int* __restrict__ chunkcnt,
                                                        const int* __restrict__ chunkrows,
                                                        u64* __restrict__ rowbest) {
    const int c = blockIdx.x;                    // chunk 0..255
    int cnt = chunkcnt[c * 16];
    if (cnt > MAXPER) cnt = MAXPER;
    if (cnt == 0) return;
    __shared__ float cl[32][260];                // +4 pad: conflict-free b128 column reads
    const int t = threadIdx.x;
    for (int u = t; u < 32 * 64; u += 256) {
        int code = u >> 6, kq = u & 63;
        *(float4*)&cl[code][kq * 4] = *(const float4*)&cbf[(size_t)(c * 32 + code) * 256 + kq * 4];
    }
    __syncthreads();
    const int wid = t >> 6, lane = t & 63;
    const int rsub = lane >> 4, lq = lane & 15;

    for (int i0 = blockIdx.y * 16 + wid * 4; i0 < cnt; i0 += 128) {
        int i = i0 + rsub;
        bool valid = i < cnt;
        int row = chunkrows[c * MAXPER + (valid ? i : 0)];
        const float* zp = zrow + (size_t)row * 256;
        float Ai = Arow[row];
        float C0 = 0.0f, C1 = 0.0f;
        #pragma unroll 8
        for (int kq = 0; kq < 64; ++kq) {
            float4 zv = *(const float4*)&zp[kq * 4];          // 16-lane broadcast
            float4 c0 = *(const float4*)&cl[lq][kq * 4];
            float4 c1 = *(const float4*)&cl[lq + 16][kq * 4];
            C0 = __builtin_fmaf(zv.x, c0.x, C0); C1 = __builtin_fmaf(zv.x, c1.x, C1);
            C0 = __builtin_fmaf(zv.y, c0.y, C0); C1 = __builtin_fmaf(zv.y, c1.y, C1);
            C0 = __builtin_fmaf(zv.z, c0.z, C0); C1 = __builtin_fmaf(zv.z, c1.z, C1);
            C0 = __builtin_fmaf(zv.w, c0.w, C0); C1 = __builtin_fmaf(zv.w, c1.w, C1);
        }
        float d0 = Ai - (C0 + C0);
        float d1 = Ai - (C1 + C1);
        int j0 = c * 32 + lq, j1 = j0 + 16;
        u64 k0 = ((u64)__float_as_uint(d0) << 32) | (unsigned)j0;
        u64 k1 = ((u64)__float_as_uint(d1) << 32) | (unsigned)j1;
        u64 key = k0 < k1 ? k0 : k1;
        if (!valid) key = ~0ull;
        #pragma unroll
        for (int mk = 1; mk < 16; mk <<= 1) {
            u64 o = __shfl_xor(key, mk, 64);
            if (o < key) key = o;
        }
        if (lq == 0 && valid) atomicMin(&rowbest[row], key);
    }
}

// ---- overflow refine (exact; expected never taken) ----
__global__ __launch_bounds__(256) void k_refine_ov(const float* __restrict__ zrow,
                                                   const float* __restrict__ cbf,
                                                   const float* __restrict__ Arow,
                                                   const int* __restrict__ ovcnt,
                                                   const unsigned* __restrict__ ovlist,
                                                   u64* __restrict__ rowbest) {
    int total = *ovcnt;
    if (total > OVCAP) total = OVCAP;
    for (int p = blockIdx.x * 256 + threadIdx.x; p < total; p += gridDim.x * 256) {
        unsigned e = ovlist[p];
        int row = e / NCHUNK, chunk = e % NCHUNK;
        const float* zp = zrow + (size_t)row * 256;
        float Ai = Arow[row];
        u64 best = ~0ull;
        for (int q = 0; q < 32; ++q) {
            int j = chunk * 32 + q;
            float d = chain_d(zp, cbf + (size_t)j * 256, Ai);
            u64 key = ((u64)__float_as_uint(d) << 32) | (unsigned)j;
            if (key < best) best = key;
        }
        atomicMin(&rowbest[row], best);
    }
}

// ---- emit indices (never-taken exact full-scan fallback) ----
__global__ __launch_bounds__(256) void k_idx(const u64* __restrict__ rowbest,
                                             const float* __restrict__ zrow,
                                             const float* __restrict__ cbf,
                                             const float* __restrict__ Arow,
                                             int* __restrict__ idxw,
                                             float* __restrict__ idxf) {
    int row = blockIdx.x * 256 + threadIdx.x;   // 128 blocks
    u64 k = rowbest[row];
    int j;
    if (k != ~0ull) {
        j = (int)(k & 0xffffffffu);
    } else {
        u64 best = ~0ull;
        for (int jj = 0; jj < NE; ++jj) {
            float d = chain_d(zrow + (size_t)row * 256, cbf + (size_t)jj * 256, Arow[row]);
            u64 key = ((u64)__float_as_uint(d) << 32) | (unsigned)jj;
            if (key < best) best = key;
        }
        j = (int)(best & 0xffffffffu);
    }
    idxw[row] = j;
    idxf[row] = (float)j;
}

// ---- zq gather + fused MSE (grid-stride, one atomic per block) ----
__global__ __launch_bounds__(256) void k_zq_mse(const float* __restrict__ z,
                                                const float* __restrict__ cbf,
                                                const int* __restrict__ idxw,
                                                float* __restrict__ zq,
                                                double* __restrict__ msesum) {
    double loc = 0.0;
    for (int i4 = blockIdx.x * 256 + threadIdx.x; i4 < NROWS * 64; i4 += 1024 * 256) {
        int id = i4 << 2;
        int w0 = (i4 & 7) * 4;
        int h = (i4 >> 3) & 31;
        int c = (i4 >> 8) & 255;
        int b = i4 >> 16;
        int nbase = (b * 32 + h) * 32 + w0;
        int4 j4 = *(const int4*)&idxw[nbase];
        float4 zv = *(const float4*)&z[id];
        float4 qv;
        qv.x = cbf[(size_t)j4.x * 256 + c];
        qv.y = cbf[(size_t)j4.y * 256 + c];
        qv.z = cbf[(size_t)j4.z * 256 + c];
        qv.w = cbf[(size_t)j4.w * 256 + c];
        *(float4*)&zq[id] = qv;
        double d0 = (double)qv.x - (double)zv.x;
        double d1 = (double)qv.y - (double)zv.y;
        double d2 = (double)qv.z - (double)zv.z;
        double d3 = (double)qv.w - (double)zv.w;
        loc += d0 * d0 + d1 * d1 + d2 * d2 + d3 * d3;
    }
    #pragma unroll
    for (int mk = 1; mk < 64; mk <<= 1) loc += __shfl_xor(loc, mk, 64);
    __shared__ double wsum[4];
    int lane = threadIdx.x & 63, wid = threadIdx.x >> 6;
    if (lane == 0) wsum[wid] = loc;
    __syncthreads();
    if (threadIdx.x == 0) {
        double tot = wsum[0] + wsum[1] + wsum[2] + wsum[3];
        atomicAdd(msesum, tot);
    }
}

// ---- finalize scalars ----
__global__ void k_final(const double* __restrict__ msesum, float* __restrict__ outs) {
    double mse = *msesum / (double)(32.0 * 256.0 * 32.0 * 32.0);
    outs[0] = (float)(1.25 * mse);   // loss
    outs[1] = (float)(0.25 * mse);   // commitment_loss
    outs[2] = (float)mse;            // codebook_loss
}

extern "C" void kernel_launch(void* const* d_in, const int* in_sizes, int n_in,
                              void* d_out, int out_size, void* d_ws, size_t ws_size,
                              hipStream_t stream) {
    const float* z    = (const float*)d_in[0];
    const float* emb  = (const float*)d_in[1];
    const float* proj = (const float*)d_in[2];
    float* out = (float*)d_out;

    char* ws = (char*)d_ws;
    size_t o = 0;
    float*    cbf       = (float*)   (ws + o); o += (size_t)NE * 256 * 4;       // 8 MB
    u16*      cbh       = (u16*)     (ws + o); o += (size_t)NE * 256 * 2;       // 4 MB
    float*    zrow      = (float*)   (ws + o); o += (size_t)NROWS * 256 * 4;    // 32 MB
    u16*      zf        = (u16*)     (ws + o); o += (size_t)NROWS * 256 * 2;    // 16 MB
    float*    Arow      = (float*)   (ws + o); o += (size_t)NROWS * 4;
    unsigned* rowmaxi   = (unsigned*)(ws + o); o += (size_t)NROWS * 4;
    unsigned* pmax32    = (unsigned*)(ws + o); o += (size_t)NROWS * 128 * 4;    // 16 MB
    int*      chunkcnt  = (int*)     (ws + o); o += (size_t)NCHUNK * 16 * 4;    // padded
    int*      chunkrows = (int*)     (ws + o); o += (size_t)NCHUNK * MAXPER * 4; // 1 MB
    int*      ovcnt     = (int*)     (ws + o); o += 64;
    unsigned* ovlist    = (unsigned*)(ws + o); o += (size_t)OVCAP * 4;          // 1 MB
    u64*      rowbest   = (u64*)     (ws + o); o += (size_t)NROWS * 8;          // 256 KB
    int*      idxw      = (int*)     (ws + o); o += (size_t)NROWS * 4;
    double*   msesum    = (double*)  (ws + o); o += 64;
    if (o > ws_size) return;

    hipMemsetAsync(rowmaxi, 0, (size_t)NROWS * 4, stream);        // encode(-inf)
    hipMemsetAsync(chunkcnt, 0, (size_t)NCHUNK * 16 * 4, stream);
    hipMemsetAsync(ovcnt, 0, 64, stream);
    hipMemsetAsync(rowbest, 0xFF, (size_t)NROWS * 8, stream);     // ~0ull
    hipMemsetAsync(msesum, 0, 8, stream);

    k_cbchain<<<dim3(256),  dim3(256), 0, stream>>>(emb, proj, cbf, cbh);
    k_zrow<<<dim3(1024), dim3(256), 0, stream>>>(z, zrow, zf, Arow);
    k_screenmax<<<dim3(16384), dim3(256), 0, stream>>>(zf, cbh, rowmaxi, pmax32);
    k_flag<<<dim3(NROWS / 256), dim3(256), 0, stream>>>(rowmaxi, pmax32, chunkcnt, chunkrows, ovcnt, ovlist);
    k_refine_bychunk<<<dim3(NCHUNK, 8), dim3(256), 0, stream>>>(zrow, cbf, Arow, chunkcnt, chunkrows, rowbest);
    k_refine_ov<<<dim3(64), dim3(256), 0, stream>>>(zrow, cbf, Arow, ovcnt, ovlist, rowbest);
    k_idx<<<dim3(NROWS / 256), dim3(256), 0, stream>>>(rowbest, zrow, cbf, Arow, idxw, out + 8388611);
    k_zq_mse<<<dim3(1024), dim3(256), 0, stream>>>(z, cbf, idxw, out, msesum);
    k_final<<<dim3(1), dim3(1), 0, stream>>>(msesum, out + 8388608);
}

// Round 11
// 718.686 us; speedup vs baseline: 2.9557x; 1.1799x over previous
//
#include <hip/hip_runtime.h>
#include <hip/hip_bf16.h>
#include <stdint.h>

#define B_ 32
#define H_ 32
#define W_ 32
#define NE 8192
#define NROWS 32768
#define K_ 256

#define MARGIN 4.0e-4f
#define NCHUNK 256          // 32-j chunks
#define MAXPER 1024
#define OVCAP (256 * 1024)

typedef unsigned short u16;
typedef unsigned long long u64;
typedef __attribute__((ext_vector_type(8))) short short8;
typedef __attribute__((ext_vector_type(4))) float f32x4;
typedef __attribute__((ext_vector_type(4))) unsigned short us4;

__device__ __forceinline__ u16 f2bf(float f) {
    union { float f; uint32_t u; } v; v.f = f;
    uint32_t u = v.u;
    uint32_t r = (u + 0x7fffu + ((u >> 16) & 1u)) >> 16;
    return (u16)r;
}

__device__ __forceinline__ unsigned fenc(float f) {
    unsigned b = __float_as_uint(f);
    return (b & 0x80000000u) ? ~b : (b | 0x80000000u);
}
__device__ __forceinline__ float fdec(unsigned e) {
    return (e & 0x80000000u) ? __uint_as_float(e & 0x7fffffffu) : __uint_as_float(~e);
}
// monotone u16 upper-bound encoding (round-up in fenc domain) — r9-proven
__device__ __forceinline__ u16 enc16ub(float f) {
    unsigned e = fenc(f);
    return (u16)((e >> 16) + ((e & 0xFFFFu) ? 1u : 0u));
}

__device__ __forceinline__ void gload_lds16(const u16* g, u16* l) {
    __builtin_amdgcn_global_load_lds((const __attribute__((address_space(1))) void*)g,
                                     (__attribute__((address_space(3))) void*)l, 16, 0, 0);
}

// exact fp32 fma chain distance (k ascending, single accumulator) — verified r3 semantics
__device__ __forceinline__ float chain_d(const float* zp, const float* cp, float Ai) {
    float C = 0.0f;
    #pragma unroll 8
    for (int kq = 0; kq < 64; ++kq) {
        float4 zv = *(const float4*)&zp[kq * 4];
        float4 cv = *(const float4*)&cp[kq * 4];
        C = __builtin_fmaf(zv.x, cv.x, C);
        C = __builtin_fmaf(zv.y, cv.y, C);
        C = __builtin_fmaf(zv.z, cv.z, C);
        C = __builtin_fmaf(zv.w, cv.w, C);
    }
    return Ai - (C + C);
}

// ---- cb = emb @ proj^T : fp32 single-accumulator fma chain over k (BLAS replica) + bf16 copy ----
__global__ __launch_bounds__(256, 2) void k_cbchain(const float* __restrict__ emb,
                                                    const float* __restrict__ proj,
                                                    float* __restrict__ cbf,
                                                    u16* __restrict__ cbh) {
    __shared__ float pl[256][65];
    __shared__ float el[32][65];
    const int t = threadIdx.x;      // output column (proj row)
    const int jb = blockIdx.x;      // 256 blocks x 32 codes
    float acc[32];
    #pragma unroll
    for (int j = 0; j < 32; ++j) acc[j] = 0.0f;
    for (int kc = 0; kc < 4; ++kc) {
        __syncthreads();
        for (int rep = 0; rep < 64; ++rep) {
            int idx = rep * 256 + t;
            int row = idx >> 6, k = idx & 63;
            pl[row][k] = proj[(size_t)row * 256 + kc * 64 + k];
        }
        for (int rep = 0; rep < 8; ++rep) {
            int idx = rep * 256 + t;
            int row = idx >> 6, k = idx & 63;
            el[row][k] = emb[(size_t)(jb * 32 + row) * 256 + kc * 64 + k];
        }
        __syncthreads();
        for (int k = 0; k < 64; ++k) {
            float p = pl[t][k];
            #pragma unroll
            for (int j = 0; j < 32; ++j)
                acc[j] = __builtin_fmaf(el[j][k], p, acc[j]);   // k ascending, single chain
        }
    }
    for (int j = 0; j < 32; ++j) {
        size_t off = (size_t)(jb * 32 + j) * 256 + t;
        cbf[off] = acc[j];
        cbh[off] = f2bf(acc[j]);
    }
}

// ---- z[b][c][h][w] -> zrow fp32 [n][c] + zf bf16 + A[n]=||z_n||^2 ----
__global__ __launch_bounds__(256) void k_zrow(const float* __restrict__ z,
                                              float* __restrict__ zrow,
                                              u16* __restrict__ zf,
                                              float* __restrict__ Arow) {
    int bh = blockIdx.x;          // 1024 = b*32+h
    int b = bh >> 5, h = bh & 31;
    __shared__ float tile[32][257];
    __shared__ double dsum[8][32];
    int t = threadIdx.x;
    int w = t & 31, cofs = t >> 5;
    double s = 0.0;
    for (int c0 = 0; c0 < 256; c0 += 8) {
        int c = c0 + cofs;
        float v = z[(((size_t)b * 256 + c) * H_ + h) * W_ + w];
        tile[w][c] = v;
        s = fma((double)v, (double)v, s);
    }
    dsum[cofs][w] = s;
    __syncthreads();
    int n0 = (b * H_ + h) * W_;
    if (t < 32) {
        double tot = 0.0;
        #pragma unroll
        for (int q = 0; q < 8; ++q) tot += dsum[q][t];
        Arow[n0 + t] = (float)tot;   // any representable fp32 works (tie-grid invariance, r3)
    }
    for (int rep = 0; rep < 8; ++rep) {
        int uid = rep * 256 + t;
        int ww = uid >> 6, u = uid & 63;
        float4 v;
        v.x = tile[ww][u * 4 + 0];
        v.y = tile[ww][u * 4 + 1];
        v.z = tile[ww][u * 4 + 2];
        v.w = tile[ww][u * 4 + 3];
        *(float4*)&zrow[((size_t)(n0 + ww)) * 256 + u * 4] = v;
        us4 bv;
        bv.x = f2bf(v.x); bv.y = f2bf(v.y); bv.z = f2bf(v.z); bv.w = f2bf(v.w);
        *(us4*)&zf[((size_t)(n0 + ww)) * 256 + u * 4] = bv;
    }
}

// ---- full-K screen GEMM: A in registers, B full-K LDS double-buffer, 1 barrier/tile ----
// grid 512 = 256 bm x 2 j-groups. Block: 4 waves (wr 2 x wc 2) over 128 rows x 64 j per tile.
// Writes pmaxT[chunk][row] (u16 round-up chunk max), chunk = 32-j granule.
__global__ __launch_bounds__(256) void k_screen3(const u16* __restrict__ zf,
                                                 const u16* __restrict__ cbh,
                                                 u16* __restrict__ pmaxT) {
    __shared__ u16 Bs[2][64 * 256];   // 2 x 32 KB
    const int t = threadIdx.x;
    const int wid = t >> 6, lane = t & 63;
    const int lr = lane & 15, lg = lane >> 4;
    const int bm = blockIdx.x >> 1;
    const int g = blockIdx.x & 1;
    const int wr = wid >> 1, wc = wid & 1;
    const int wrow = bm * 128 + wr * 64;

    // A fragments: rows wrow + m*16 + lr, full K, straight from zf (one-time)
    short8 a[4][8];
    #pragma unroll
    for (int m = 0; m < 4; ++m) {
        const u16* zp = zf + (size_t)(wrow + m * 16 + lr) * 256 + lg * 8;
        #pragma unroll
        for (int ks = 0; ks < 8; ++ks)
            a[m][ks] = *(const short8*)&zp[ks * 32];
    }

    // staging source offsets (u16 units; row/unit XOR pre-swizzle, rule 21)
    int soff[8];
    #pragma unroll
    for (int s = 0; s < 8; ++s) {
        int c = s * 4 + wid;
        int row = c * 2 + (lane >> 5);
        int ug = (lane & 31) ^ (row & 7);
        soff[s] = row * 256 + ug * 8;
    }

    // b-frag LDS read addresses (swizzled), loop-invariant per lane
    const int rowb0 = wc * 32 + lr;
    const int rowb1 = rowb0 + 16;
    int baddr0[8], baddr1[8];
    #pragma unroll
    for (int ks = 0; ks < 8; ++ks) {
        baddr0[ks] = rowb0 * 256 + (((ks * 4 + lg) ^ (rowb0 & 7)) * 8);
        baddr1[ks] = rowb1 * 256 + (((ks * 4 + lg) ^ (rowb1 & 7)) * 8);
    }

    auto stage = [&](int buf, int tile) {
        const u16* base = cbh + (size_t)(g * 4096 + tile * 64) * 256;
        #pragma unroll
        for (int s = 0; s < 8; ++s)
            gload_lds16(base + soff[s], &Bs[buf][(s * 4 + wid) * 512]);
    };

    stage(0, 0);
    __syncthreads();
    int cur = 0;
    for (int tile = 0; tile < 64; ++tile) {
        if (tile < 63) stage(cur ^ 1, tile + 1);
        f32x4 acc[4][2] = {};
        #pragma unroll
        for (int ks = 0; ks < 8; ++ks) {
            short8 b0 = *(const short8*)&Bs[cur][baddr0[ks]];
            short8 b1 = *(const short8*)&Bs[cur][baddr1[ks]];
            #pragma unroll
            for (int m = 0; m < 4; ++m) {
                acc[m][0] = __builtin_amdgcn_mfma_f32_16x16x32_bf16(a[m][ks], b0, acc[m][0], 0, 0, 0);
                acc[m][1] = __builtin_amdgcn_mfma_f32_16x16x32_bf16(a[m][ks], b1, acc[m][1], 0, 0, 0);
            }
        }
        // epilogue: per-row 32-j chunk max; f32 shfl reduce over the 16-lane lr group
        int chunk = g * 128 + tile * 2 + wc;
        #pragma unroll
        for (int m = 0; m < 4; ++m) {
            float v[4];
            #pragma unroll
            for (int r = 0; r < 4; ++r) {
                float x = fmaxf(acc[m][0][r], acc[m][1][r]);
                #pragma unroll
                for (int mk = 1; mk < 16; mk <<= 1) x = fmaxf(x, __shfl_xor(x, mk, 64));
                v[r] = x;
            }
            if (lr == 0) {
                us4 pack;
                pack.x = enc16ub(v[0]); pack.y = enc16ub(v[1]);
                pack.z = enc16ub(v[2]); pack.w = enc16ub(v[3]);
                *(us4*)&pmaxT[(size_t)chunk * NROWS + wrow + m * 16 + lg * 4] = pack;
            }
        }
        __syncthreads();
        cur ^= 1;
    }
}

// ---- rowmax + flag chunks >= thr into per-chunk row buckets (chunk-major coalesced reads) ----
__global__ __launch_bounds__(256) void k_flag(const u16* __restrict__ pmaxT,
                                              int* __restrict__ chunkcnt,     // stride 16 (pad)
                                              int* __restrict__ chunkrows,
                                              int* __restrict__ ovcnt,
                                              unsigned* __restrict__ ovlist) {
    int row = blockIdx.x * 256 + threadIdx.x;   // 128 blocks
    float rm = -3.0e38f;
    for (int c = 0; c < NCHUNK; ++c)
        rm = fmaxf(rm, fdec((unsigned)pmaxT[(size_t)c * NROWS + row] << 16));
    float thr = rm - MARGIN;
    for (int c = 0; c < NCHUNK; ++c) {
        float f = fdec((unsigned)pmaxT[(size_t)c * NROWS + row] << 16);
        if (f >= thr) {
            int slot = atomicAdd(&chunkcnt[c * 16], 1);
            if (slot < MAXPER) {
                chunkrows[c * MAXPER + slot] = row;
            } else {
                int op = atomicAdd(ovcnt, 1);
                if (op < OVCAP) ovlist[op] = (unsigned)(row * NCHUNK + c);
            }
        }
    }
}

// ---- refine by chunk: stage 32 codes of cbf in LDS once, reuse across bucket rows ----
__global__ __launch_bounds__(256) void k_refine_bychunk(const float* __restrict__ zrow,
                                                        const float* __restrict__ cbf,
                                                        const float* __restrict__ Arow,
                                                        const int* __restrict__ chunkcnt,
                                                        const int* __restrict__ chunkrows,
                                                        u64* __restrict__ rowbest) {
    const int c = blockIdx.x;                    // chunk 0..255
    int cnt = chunkcnt[c * 16];
    if (cnt > MAXPER) cnt = MAXPER;
    if (cnt == 0) return;
    __shared__ float cl[32][260];                // +4 pad: conflict-free b128 column reads
    const int t = threadIdx.x;
    for (int u = t; u < 32 * 64; u += 256) {
        int code = u >> 6, kq = u & 63;
        *(float4*)&cl[code][kq * 4] = *(const float4*)&cbf[(size_t)(c * 32 + code) * 256 + kq * 4];
    }
    __syncthreads();
    const int wid = t >> 6, lane = t & 63;
    const int rsub = lane >> 4, lq = lane & 15;

    for (int i0 = blockIdx.y * 16 + wid * 4; i0 < cnt; i0 += 128) {
        int i = i0 + rsub;
        bool valid = i < cnt;
        int row = chunkrows[c * MAXPER + (valid ? i : 0)];
        const float* zp = zrow + (size_t)row * 256;
        float Ai = Arow[row];
        float C0 = 0.0f, C1 = 0.0f;
        #pragma unroll 8
        for (int kq = 0; kq < 64; ++kq) {
            float4 zv = *(const float4*)&zp[kq * 4];          // 16-lane broadcast
            float4 c0 = *(const float4*)&cl[lq][kq * 4];
            float4 c1 = *(const float4*)&cl[lq + 16][kq * 4];
            C0 = __builtin_fmaf(zv.x, c0.x, C0); C1 = __builtin_fmaf(zv.x, c1.x, C1);
            C0 = __builtin_fmaf(zv.y, c0.y, C0); C1 = __builtin_fmaf(zv.y, c1.y, C1);
            C0 = __builtin_fmaf(zv.z, c0.z, C0); C1 = __builtin_fmaf(zv.z, c1.z, C1);
            C0 = __builtin_fmaf(zv.w, c0.w, C0); C1 = __builtin_fmaf(zv.w, c1.w, C1);
        }
        float d0 = Ai - (C0 + C0);
        float d1 = Ai - (C1 + C1);
        int j0 = c * 32 + lq, j1 = j0 + 16;
        u64 k0 = ((u64)__float_as_uint(d0) << 32) | (unsigned)j0;
        u64 k1 = ((u64)__float_as_uint(d1) << 32) | (unsigned)j1;
        u64 key = k0 < k1 ? k0 : k1;
        if (!valid) key = ~0ull;
        #pragma unroll
        for (int mk = 1; mk < 16; mk <<= 1) {
            u64 o = __shfl_xor(key, mk, 64);
            if (o < key) key = o;
        }
        if (lq == 0 && valid) atomicMin(&rowbest[row], key);
    }
}

// ---- overflow refine (exact; expected never taken) ----
__global__ __launch_bounds__(256) void k_refine_ov(const float* __restrict__ zrow,
                                                   const float* __restrict__ cbf,
                                                   const float* __restrict__ Arow,
                                                   const int* __restrict__ ovcnt,
                                                   const unsigned* __restrict__ ovlist,
                                                   u64* __restrict__ rowbest) {
    int total = *ovcnt;
    if (total > OVCAP) total = OVCAP;
    for (int p = blockIdx.x * 256 + threadIdx.x; p < total; p += gridDim.x * 256) {
        unsigned e = ovlist[p];
        int row = e / NCHUNK, chunk = e % NCHUNK;
        const float* zp = zrow + (size_t)row * 256;
        float Ai = Arow[row];
        u64 best = ~0ull;
        for (int q = 0; q < 32; ++q) {
            int j = chunk * 32 + q;
            float d = chain_d(zp, cbf + (size_t)j * 256, Ai);
            u64 key = ((u64)__float_as_uint(d) << 32) | (unsigned)j;
            if (key < best) best = key;
        }
        atomicMin(&rowbest[row], best);
    }
}

// ---- emit indices (never-taken exact full-scan fallback) ----
__global__ __launch_bounds__(256) void k_idx(const u64* __restrict__ rowbest,
                                             const float* __restrict__ zrow,
                                             const float* __restrict__ cbf,
                                             const float* __restrict__ Arow,
                                             int* __restrict__ idxw,
                                             float* __restrict__ idxf) {
    int row = blockIdx.x * 256 + threadIdx.x;   // 128 blocks
    u64 k = rowbest[row];
    int j;
    if (k != ~0ull) {
        j = (int)(k & 0xffffffffu);
    } else {
        u64 best = ~0ull;
        for (int jj = 0; jj < NE; ++jj) {
            float d = chain_d(zrow + (size_t)row * 256, cbf + (size_t)jj * 256, Arow[row]);
            u64 key = ((u64)__float_as_uint(d) << 32) | (unsigned)jj;
            if (key < best) best = key;
        }
        j = (int)(best & 0xffffffffu);
    }
    idxw[row] = j;
    idxf[row] = (float)j;
}

// ---- zq gather + fused MSE (grid-stride, one atomic per block) ----
__global__ __launch_bounds__(256) void k_zq_mse(const float* __restrict__ z,
                                                const float* __restrict__ cbf,
                                                const int* __restrict__ idxw,
                                                float* __restrict__ zq,
                                                double* __restrict__ msesum) {
    double loc = 0.0;
    for (int i4 = blockIdx.x * 256 + threadIdx.x; i4 < NROWS * 64; i4 += 1024 * 256) {
        int id = i4 << 2;
        int w0 = (i4 & 7) * 4;
        int h = (i4 >> 3) & 31;
        int c = (i4 >> 8) & 255;
        int b = i4 >> 16;
        int nbase = (b * 32 + h) * 32 + w0;
        int4 j4 = *(const int4*)&idxw[nbase];
        float4 zv = *(const float4*)&z[id];
        float4 qv;
        qv.x = cbf[(size_t)j4.x * 256 + c];
        qv.y = cbf[(size_t)j4.y * 256 + c];
        qv.z = cbf[(size_t)j4.z * 256 + c];
        qv.w = cbf[(size_t)j4.w * 256 + c];
        *(float4*)&zq[id] = qv;
        double d0 = (double)qv.x - (double)zv.x;
        double d1 = (double)qv.y - (double)zv.y;
        double d2 = (double)qv.z - (double)zv.z;
        double d3 = (double)qv.w - (double)zv.w;
        loc += d0 * d0 + d1 * d1 + d2 * d2 + d3 * d3;
    }
    #pragma unroll
    for (int mk = 1; mk < 64; mk <<= 1) loc += __shfl_xor(loc, mk, 64);
    __shared__ double wsum[4];
    int lane = threadIdx.x & 63, wid = threadIdx.x >> 6;
    if (lane == 0) wsum[wid] = loc;
    __syncthreads();
    if (threadIdx.x == 0) {
        double tot = wsum[0] + wsum[1] + wsum[2] + wsum[3];
        atomicAdd(msesum, tot);
    }
}

// ---- finalize scalars ----
__global__ void k_final(const double* __restrict__ msesum, float* __restrict__ outs) {
    double mse = *msesum / (double)(32.0 * 256.0 * 32.0 * 32.0);
    outs[0] = (float)(1.25 * mse);   // loss
    outs[1] = (float)(0.25 * mse);   // commitment_loss
    outs[2] = (float)mse;            // codebook_loss
}

extern "C" void kernel_launch(void* const* d_in, const int* in_sizes, int n_in,
                              void* d_out, int out_size, void* d_ws, size_t ws_size,
                              hipStream_t stream) {
    const float* z    = (const float*)d_in[0];
    const float* emb  = (const float*)d_in[1];
    const float* proj = (const float*)d_in[2];
    float* out = (float*)d_out;

    char* ws = (char*)d_ws;
    size_t o = 0;
    float*    cbf       = (float*)   (ws + o); o += (size_t)NE * 256 * 4;        // 8 MB
    u16*      cbh       = (u16*)     (ws + o); o += (size_t)NE * 256 * 2;        // 4 MB
    float*    zrow      = (float*)   (ws + o); o += (size_t)NROWS * 256 * 4;     // 32 MB
    u16*      zf        = (u16*)     (ws + o); o += (size_t)NROWS * 256 * 2;     // 16 MB
    float*    Arow      = (float*)   (ws + o); o += (size_t)NROWS * 4;
    u16*      pmaxT     = (u16*)     (ws + o); o += (size_t)NCHUNK * NROWS * 2;  // 16 MB
    int*      chunkcnt  = (int*)     (ws + o); o += (size_t)NCHUNK * 16 * 4;     // padded
    int*      chunkrows = (int*)     (ws + o); o += (size_t)NCHUNK * MAXPER * 4; // 1 MB
    int*      ovcnt     = (int*)     (ws + o); o += 64;
    unsigned* ovlist    = (unsigned*)(ws + o); o += (size_t)OVCAP * 4;           // 1 MB
    u64*      rowbest   = (u64*)     (ws + o); o += (size_t)NROWS * 8;           // 256 KB
    int*      idxw      = (int*)     (ws + o); o += (size_t)NROWS * 4;
    double*   msesum    = (double*)  (ws + o); o += 64;
    if (o > ws_size) return;

    hipMemsetAsync(chunkcnt, 0, (size_t)NCHUNK * 16 * 4, stream);
    hipMemsetAsync(ovcnt, 0, 64, stream);
    hipMemsetAsync(rowbest, 0xFF, (size_t)NROWS * 8, stream);     // ~0ull
    hipMemsetAsync(msesum, 0, 8, stream);

    k_cbchain<<<dim3(256),  dim3(256), 0, stream>>>(emb, proj, cbf, cbh);
    k_zrow<<<dim3(1024), dim3(256), 0, stream>>>(z, zrow, zf, Arow);
    k_screen3<<<dim3(512), dim3(256), 0, stream>>>(zf, cbh, pmaxT);
    k_flag<<<dim3(NROWS / 256), dim3(256), 0, stream>>>(pmaxT, chunkcnt, chunkrows, ovcnt, ovlist);
    k_refine_bychunk<<<dim3(NCHUNK, 8), dim3(256), 0, stream>>>(zrow, cbf, Arow, chunkcnt, chunkrows, rowbest);
    k_refine_ov<<<dim3(64), dim3(256), 0, stream>>>(zrow, cbf, Arow, ovcnt, ovlist, rowbest);
    k_idx<<<dim3(NROWS / 256), dim3(256), 0, stream>>>(rowbest, zrow, cbf, Arow, idxw, out + 8388611);
    k_zq_mse<<<dim3(1024), dim3(256), 0, stream>>>(z, cbf, idxw, out, msesum);
    k_final<<<dim3(1), dim3(1), 0, stream>>>(msesum, out + 8388608);
}

// Round 12
// 659.210 us; speedup vs baseline: 3.2224x; 1.0902x over previous
//
#include <hip/hip_runtime.h>
#include <hip/hip_bf16.h>
#include <stdint.h>

#define B_ 32
#define H_ 32
#define W_ 32
#define NE 8192
#define NROWS 32768
#define K_ 256

#define MARGIN 4.0e-4f
#define NCHUNK 256          // 32-j chunks
#define MAXPER 8192
#define OVCAP (256 * 1024)

typedef unsigned short u16;
typedef unsigned long long u64;
typedef __attribute__((ext_vector_type(8))) short short8;
typedef __attribute__((ext_vector_type(4))) float f32x4;
typedef __attribute__((ext_vector_type(4))) unsigned short us4;

__device__ __forceinline__ u16 f2bf(float f) {
    union { float f; uint32_t u; } v; v.f = f;
    uint32_t u = v.u;
    uint32_t r = (u + 0x7fffu + ((u >> 16) & 1u)) >> 16;
    return (u16)r;
}

__device__ __forceinline__ unsigned fenc(float f) {
    unsigned b = __float_as_uint(f);
    return (b & 0x80000000u) ? ~b : (b | 0x80000000u);
}
__device__ __forceinline__ float fdec(unsigned e) {
    return (e & 0x80000000u) ? __uint_as_float(e & 0x7fffffffu) : __uint_as_float(~e);
}
// monotone u16 upper-bound encoding (round-up in fenc domain) — r9-proven
__device__ __forceinline__ u16 enc16ub(float f) {
    unsigned e = fenc(f);
    return (u16)((e >> 16) + ((e & 0xFFFFu) ? 1u : 0u));
}

// DPP row_ror rotate-reduce step (VALU pipe; 16-lane physical row == our lr group)
template<int N>
__device__ __forceinline__ float dppror(float v) {
    int x = __builtin_amdgcn_mov_dpp(__float_as_int(v), 0x120 + N, 0xf, 0xf, true);
    return __int_as_float(x);
}

__device__ __forceinline__ void gload_lds16(const u16* g, u16* l) {
    __builtin_amdgcn_global_load_lds((const __attribute__((address_space(1))) void*)g,
                                     (__attribute__((address_space(3))) void*)l, 16, 0, 0);
}

// exact fp32 fma chain distance (k ascending, single accumulator) — verified r3 semantics
__device__ __forceinline__ float chain_d(const float* zp, const float* cp, float Ai) {
    float C = 0.0f;
    #pragma unroll 8
    for (int kq = 0; kq < 64; ++kq) {
        float4 zv = *(const float4*)&zp[kq * 4];
        float4 cv = *(const float4*)&cp[kq * 4];
        C = __builtin_fmaf(zv.x, cv.x, C);
        C = __builtin_fmaf(zv.y, cv.y, C);
        C = __builtin_fmaf(zv.z, cv.z, C);
        C = __builtin_fmaf(zv.w, cv.w, C);
    }
    return Ai - (C + C);
}

// ---- cb = emb @ proj^T : fp32 single-accumulator fma chain over k (BLAS replica) + bf16 copy ----
__global__ __launch_bounds__(256, 2) void k_cbchain(const float* __restrict__ emb,
                                                    const float* __restrict__ proj,
                                                    float* __restrict__ cbf,
                                                    u16* __restrict__ cbh) {
    __shared__ float pl[256][65];
    __shared__ float el[32][65];
    const int t = threadIdx.x;      // output column (proj row)
    const int jb = blockIdx.x;      // 256 blocks x 32 codes
    float acc[32];
    #pragma unroll
    for (int j = 0; j < 32; ++j) acc[j] = 0.0f;
    for (int kc = 0; kc < 4; ++kc) {
        __syncthreads();
        for (int rep = 0; rep < 64; ++rep) {
            int idx = rep * 256 + t;
            int row = idx >> 6, k = idx & 63;
            pl[row][k] = proj[(size_t)row * 256 + kc * 64 + k];
        }
        for (int rep = 0; rep < 8; ++rep) {
            int idx = rep * 256 + t;
            int row = idx >> 6, k = idx & 63;
            el[row][k] = emb[(size_t)(jb * 32 + row) * 256 + kc * 64 + k];
        }
        __syncthreads();
        for (int k = 0; k < 64; ++k) {
            float p = pl[t][k];
            #pragma unroll
            for (int j = 0; j < 32; ++j)
                acc[j] = __builtin_fmaf(el[j][k], p, acc[j]);   // k ascending, single chain
        }
    }
    for (int j = 0; j < 32; ++j) {
        size_t off = (size_t)(jb * 32 + j) * 256 + t;
        cbf[off] = acc[j];
        cbh[off] = f2bf(acc[j]);
    }
}

// ---- z[b][c][h][w] -> zrow fp32 [n][c] + zf bf16 + A[n]=||z_n||^2 ----
__global__ __launch_bounds__(256) void k_zrow(const float* __restrict__ z,
                                              float* __restrict__ zrow,
                                              u16* __restrict__ zf,
                                              float* __restrict__ Arow) {
    int bh = blockIdx.x;          // 1024 = b*32+h
    int b = bh >> 5, h = bh & 31;
    __shared__ float tile[32][257];
    __shared__ double dsum[8][32];
    int t = threadIdx.x;
    int w = t & 31, cofs = t >> 5;
    double s = 0.0;
    for (int c0 = 0; c0 < 256; c0 += 8) {
        int c = c0 + cofs;
        float v = z[(((size_t)b * 256 + c) * H_ + h) * W_ + w];
        tile[w][c] = v;
        s = fma((double)v, (double)v, s);
    }
    dsum[cofs][w] = s;
    __syncthreads();
    int n0 = (b * H_ + h) * W_;
    if (t < 32) {
        double tot = 0.0;
        #pragma unroll
        for (int q = 0; q < 8; ++q) tot += dsum[q][t];
        Arow[n0 + t] = (float)tot;   // any representable fp32 works (tie-grid invariance, r3)
    }
    for (int rep = 0; rep < 8; ++rep) {
        int uid = rep * 256 + t;
        int ww = uid >> 6, u = uid & 63;
        float4 v;
        v.x = tile[ww][u * 4 + 0];
        v.y = tile[ww][u * 4 + 1];
        v.z = tile[ww][u * 4 + 2];
        v.w = tile[ww][u * 4 + 3];
        *(float4*)&zrow[((size_t)(n0 + ww)) * 256 + u * 4] = v;
        us4 bv;
        bv.x = f2bf(v.x); bv.y = f2bf(v.y); bv.z = f2bf(v.z); bv.w = f2bf(v.w);
        *(us4*)&zf[((size_t)(n0 + ww)) * 256 + u * 4] = bv;
    }
}

// ---- full-K screen GEMM: A in registers, B full-K LDS double-buffer, 1 barrier/tile ----
// grid 512 = 256 bm x 2 j-groups. Block: 4 waves (wr 2 x wc 2) over 128 rows x 64 j per tile.
// Epilogue: DPP row_ror rotate-reduce (VALU, no DS ops). Writes pmaxT[chunk][row] u16 round-up.
__global__ __launch_bounds__(256) void k_screen3(const u16* __restrict__ zf,
                                                 const u16* __restrict__ cbh,
                                                 u16* __restrict__ pmaxT) {
    __shared__ u16 Bs[2][64 * 256];   // 2 x 32 KB
    const int t = threadIdx.x;
    const int wid = t >> 6, lane = t & 63;
    const int lr = lane & 15, lg = lane >> 4;
    const int bm = blockIdx.x >> 1;
    const int g = blockIdx.x & 1;
    const int wr = wid >> 1, wc = wid & 1;
    const int wrow = bm * 128 + wr * 64;

    // A fragments: rows wrow + m*16 + lr, full K, straight from zf (one-time)
    short8 a[4][8];
    #pragma unroll
    for (int m = 0; m < 4; ++m) {
        const u16* zp = zf + (size_t)(wrow + m * 16 + lr) * 256 + lg * 8;
        #pragma unroll
        for (int ks = 0; ks < 8; ++ks)
            a[m][ks] = *(const short8*)&zp[ks * 32];
    }

    // staging source offsets (u16 units; row/unit XOR pre-swizzle, rule 21)
    int soff[8];
    #pragma unroll
    for (int s = 0; s < 8; ++s) {
        int c = s * 4 + wid;
        int row = c * 2 + (lane >> 5);
        int ug = (lane & 31) ^ (row & 7);
        soff[s] = row * 256 + ug * 8;
    }

    // b-frag LDS read addresses (swizzled), loop-invariant per lane
    const int rowb0 = wc * 32 + lr;
    const int rowb1 = rowb0 + 16;
    int baddr0[8], baddr1[8];
    #pragma unroll
    for (int ks = 0; ks < 8; ++ks) {
        baddr0[ks] = rowb0 * 256 + (((ks * 4 + lg) ^ (rowb0 & 7)) * 8);
        baddr1[ks] = rowb1 * 256 + (((ks * 4 + lg) ^ (rowb1 & 7)) * 8);
    }

    auto stage = [&](int buf, int tile) {
        const u16* base = cbh + (size_t)(g * 4096 + tile * 64) * 256;
        #pragma unroll
        for (int s = 0; s < 8; ++s)
            gload_lds16(base + soff[s], &Bs[buf][(s * 4 + wid) * 512]);
    };

    stage(0, 0);
    __syncthreads();
    int cur = 0;
    for (int tile = 0; tile < 64; ++tile) {
        if (tile < 63) stage(cur ^ 1, tile + 1);
        f32x4 acc[4][2] = {};
        #pragma unroll
        for (int ks = 0; ks < 8; ++ks) {
            short8 b0 = *(const short8*)&Bs[cur][baddr0[ks]];
            short8 b1 = *(const short8*)&Bs[cur][baddr1[ks]];
            #pragma unroll
            for (int m = 0; m < 4; ++m) {
                acc[m][0] = __builtin_amdgcn_mfma_f32_16x16x32_bf16(a[m][ks], b0, acc[m][0], 0, 0, 0);
                acc[m][1] = __builtin_amdgcn_mfma_f32_16x16x32_bf16(a[m][ks], b1, acc[m][1], 0, 0, 0);
            }
        }
        // epilogue: per-row 32-j chunk max; DPP rotate-reduce over the 16-lane lr row (VALU only)
        int chunk = g * 128 + tile * 2 + wc;
        #pragma unroll
        for (int m = 0; m < 4; ++m) {
            float v[4];
            #pragma unroll
            for (int r = 0; r < 4; ++r) {
                float x = fmaxf(acc[m][0][r], acc[m][1][r]);
                x = fmaxf(x, dppror<1>(x));
                x = fmaxf(x, dppror<2>(x));
                x = fmaxf(x, dppror<4>(x));
                x = fmaxf(x, dppror<8>(x));
                v[r] = x;
            }
            if (lr == 0) {
                us4 pack;
                pack.x = enc16ub(v[0]); pack.y = enc16ub(v[1]);
                pack.z = enc16ub(v[2]); pack.w = enc16ub(v[3]);
                *(us4*)&pmaxT[(size_t)chunk * NROWS + wrow + m * 16 + lg * 4] = pack;
            }
        }
        __syncthreads();
        cur ^= 1;
    }
}

// ---- rowmax + flag chunks >= thr into per-chunk row buckets (chunk-major coalesced reads) ----
__global__ __launch_bounds__(256) void k_flag(const u16* __restrict__ pmaxT,
                                              int* __restrict__ chunkcnt,     // stride 16 (pad)
                                              int* __restrict__ chunkrows,
                                              int* __restrict__ ovcnt,
                                              unsigned* __restrict__ ovlist) {
    int row = blockIdx.x * 256 + threadIdx.x;   // 128 blocks
    float rm = -3.0e38f;
    for (int c = 0; c < NCHUNK; ++c)
        rm = fmaxf(rm, fdec((unsigned)pmaxT[(size_t)c * NROWS + row] << 16));
    float thr = rm - MARGIN;
    for (int c = 0; c < NCHUNK; ++c) {
        float f = fdec((unsigned)pmaxT[(size_t)c * NROWS + row] << 16);
        if (f >= thr) {
            int slot = atomicAdd(&chunkcnt[c * 16], 1);
            if (slot < MAXPER) {
                chunkrows[c * MAXPER + slot] = row;
            } else {
                int op = atomicAdd(ovcnt, 1);
                if (op < OVCAP) ovlist[op] = (unsigned)(row * NCHUNK + c);
            }
        }
    }
}

// ---- refine by chunk: stage 32 codes of cbf in LDS once, reuse across bucket rows ----
__global__ __launch_bounds__(256) void k_refine_bychunk(const float* __restrict__ zrow,
                                                        const float* __restrict__ cbf,
                                                        const float* __restrict__ Arow,
                                                        const int* __restrict__ chunkcnt,
                                                        const int* __restrict__ chunkrows,
                                                        u64* __restrict__ rowbest) {
    const int c = blockIdx.x;                    // chunk 0..255
    int cnt = chunkcnt[c * 16];
    if (cnt > MAXPER) cnt = MAXPER;
    if (cnt == 0) return;
    __shared__ float cl[32][260];                // +4 pad: conflict-free b128 column reads
    const int t = threadIdx.x;
    for (int u = t; u < 32 * 64; u += 256) {
        int code = u >> 6, kq = u & 63;
        *(float4*)&cl[code][kq * 4] = *(const float4*)&cbf[(size_t)(c * 32 + code) * 256 + kq * 4];
    }
    __syncthreads();
    const int wid = t >> 6, lane = t & 63;
    const int rsub = lane >> 4, lq = lane & 15;

    for (int i0 = blockIdx.y * 16 + wid * 4; i0 < cnt; i0 += 256) {
        int i = i0 + rsub;
        bool valid = i < cnt;
        int row = chunkrows[c * MAXPER + (valid ? i : 0)];
        const float* zp = zrow + (size_t)row * 256;
        float Ai = Arow[row];
        float C0 = 0.0f, C1 = 0.0f;
        #pragma unroll 8
        for (int kq = 0; kq < 64; ++kq) {
            float4 zv = *(const float4*)&zp[kq * 4];          // 16-lane broadcast
            float4 c0 = *(const float4*)&cl[lq][kq * 4];
            float4 c1 = *(const float4*)&cl[lq + 16][kq * 4];
            C0 = __builtin_fmaf(zv.x, c0.x, C0); C1 = __builtin_fmaf(zv.x, c1.x, C1);
            C0 = __builtin_fmaf(zv.y, c0.y, C0); C1 = __builtin_fmaf(zv.y, c1.y, C1);
            C0 = __builtin_fmaf(zv.z, c0.z, C0); C1 = __builtin_fmaf(zv.z, c1.z, C1);
            C0 = __builtin_fmaf(zv.w, c0.w, C0); C1 = __builtin_fmaf(zv.w, c1.w, C1);
        }
        float d0 = Ai - (C0 + C0);
        float d1 = Ai - (C1 + C1);
        int j0 = c * 32 + lq, j1 = j0 + 16;
        u64 k0 = ((u64)__float_as_uint(d0) << 32) | (unsigned)j0;
        u64 k1 = ((u64)__float_as_uint(d1) << 32) | (unsigned)j1;
        u64 key = k0 < k1 ? k0 : k1;
        if (!valid) key = ~0ull;
        #pragma unroll
        for (int mk = 1; mk < 16; mk <<= 1) {
            u64 o = __shfl_xor(key, mk, 64);
            if (o < key) key = o;
        }
        if (lq == 0 && valid) atomicMin(&rowbest[row], key);
    }
}

// ---- overflow refine (exact; expected never taken at MAXPER=8192) ----
__global__ __launch_bounds__(256) void k_refine_ov(const float* __restrict__ zrow,
                                                   const float* __restrict__ cbf,
                                                   const float* __restrict__ Arow,
                                                   const int* __restrict__ ovcnt,
                                                   const unsigned* __restrict__ ovlist,
                                                   u64* __restrict__ rowbest) {
    int total = *ovcnt;
    if (total > OVCAP) total = OVCAP;
    for (int p = blockIdx.x * 256 + threadIdx.x; p < total; p += gridDim.x * 256) {
        unsigned e = ovlist[p];
        int row = e / NCHUNK, chunk = e % NCHUNK;
        const float* zp = zrow + (size_t)row * 256;
        float Ai = Arow[row];
        u64 best = ~0ull;
        for (int q = 0; q < 32; ++q) {
            int j = chunk * 32 + q;
            float d = chain_d(zp, cbf + (size_t)j * 256, Ai);
            u64 key = ((u64)__float_as_uint(d) << 32) | (unsigned)j;
            if (key < best) best = key;
        }
        atomicMin(&rowbest[row], best);
    }
}

// ---- emit indices (never-taken exact full-scan fallback) ----
__global__ __launch_bounds__(256) void k_idx(const u64* __restrict__ rowbest,
                                             const float* __restrict__ zrow,
                                             const float* __restrict__ cbf,
                                             const float* __restrict__ Arow,
                                             int* __restrict__ idxw,
                                             float* __restrict__ idxf) {
    int row = blockIdx.x * 256 + threadIdx.x;   // 128 blocks
    u64 k = rowbest[row];
    int j;
    if (k != ~0ull) {
        j = (int)(k & 0xffffffffu);
    } else {
        u64 best = ~0ull;
        for (int jj = 0; jj < NE; ++jj) {
            float d = chain_d(zrow + (size_t)row * 256, cbf + (size_t)jj * 256, Arow[row]);
            u64 key = ((u64)__float_as_uint(d) << 32) | (unsigned)jj;
            if (key < best) best = key;
        }
        j = (int)(best & 0xffffffffu);
    }
    idxw[row] = j;
    idxf[row] = (float)j;
}

// ---- zq gather + fused MSE: row-per-iteration, fully coalesced cbf/zrow reads ----
// grid 2048 blocks x 16 rows; per-block partial sum -> blocksum (no atomics)
__global__ __launch_bounds__(256) void k_zq_mse(const float* __restrict__ zrow,
                                                const float* __restrict__ cbf,
                                                const int* __restrict__ idxw,
                                                float* __restrict__ zq,
                                                double* __restrict__ blocksum) {
    const int t = threadIdx.x;
    const int n0 = blockIdx.x * 16;
    double loc = 0.0;
    #pragma unroll 4
    for (int i = 0; i < 16; ++i) {
        int n = n0 + i;
        int j = idxw[n];                               // wave-uniform
        float q = cbf[(size_t)j * 256 + t];            // coalesced 1KB
        float zv = zrow[(size_t)n * 256 + t];          // coalesced 1KB (bit-copy of z)
        int b = n >> 10, h = (n >> 5) & 31, w = n & 31;
        zq[(((size_t)b * 256 + t) * 32 + h) * 32 + w] = q;   // per-thread line fills across i
        double d = (double)q - (double)zv;
        loc += d * d;
    }
    #pragma unroll
    for (int mk = 1; mk < 64; mk <<= 1) loc += __shfl_xor(loc, mk, 64);
    __shared__ double wsum[4];
    int lane = t & 63, wid = t >> 6;
    if (lane == 0) wsum[wid] = loc;
    __syncthreads();
    if (t == 0) blocksum[blockIdx.x] = wsum[0] + wsum[1] + wsum[2] + wsum[3];
}

// ---- finalize scalars (sums 2048 block partials) ----
__global__ __launch_bounds__(256) void k_final(const double* __restrict__ blocksum,
                                               float* __restrict__ outs) {
    __shared__ double sh[4];
    int t = threadIdx.x;
    double s = 0.0;
    for (int i = t; i < 2048; i += 256) s += blocksum[i];
    #pragma unroll
    for (int mk = 1; mk < 64; mk <<= 1) s += __shfl_xor(s, mk, 64);
    int lane = t & 63, wid = t >> 6;
    if (lane == 0) sh[wid] = s;
    __syncthreads();
    if (t == 0) {
        double mse = (sh[0] + sh[1] + sh[2] + sh[3]) / (double)(32.0 * 256.0 * 32.0 * 32.0);
        outs[0] = (float)(1.25 * mse);   // loss
        outs[1] = (float)(0.25 * mse);   // commitment_loss
        outs[2] = (float)mse;            // codebook_loss
    }
}

extern "C" void kernel_launch(void* const* d_in, const int* in_sizes, int n_in,
                              void* d_out, int out_size, void* d_ws, size_t ws_size,
                              hipStream_t stream) {
    const float* z    = (const float*)d_in[0];
    const float* emb  = (const float*)d_in[1];
    const float* proj = (const float*)d_in[2];
    float* out = (float*)d_out;

    char* ws = (char*)d_ws;
    size_t o = 0;
    float*    cbf       = (float*)   (ws + o); o += (size_t)NE * 256 * 4;        // 8 MB
    u16*      cbh       = (u16*)     (ws + o); o += (size_t)NE * 256 * 2;        // 4 MB
    float*    zrow      = (float*)   (ws + o); o += (size_t)NROWS * 256 * 4;     // 32 MB
    u16*      zf        = (u16*)     (ws + o); o += (size_t)NROWS * 256 * 2;     // 16 MB
    float*    Arow      = (float*)   (ws + o); o += (size_t)NROWS * 4;
    u16*      pmaxT     = (u16*)     (ws + o); o += (size_t)NCHUNK * NROWS * 2;  // 16 MB
    int*      chunkcnt  = (int*)     (ws + o); o += (size_t)NCHUNK * 16 * 4;     // padded
    int*      chunkrows = (int*)     (ws + o); o += (size_t)NCHUNK * MAXPER * 4; // 8 MB
    int*      ovcnt     = (int*)     (ws + o); o += 64;
    unsigned* ovlist    = (unsigned*)(ws + o); o += (size_t)OVCAP * 4;           // 1 MB
    u64*      rowbest   = (u64*)     (ws + o); o += (size_t)NROWS * 8;           // 256 KB
    int*      idxw      = (int*)     (ws + o); o += (size_t)NROWS * 4;
    double*   blocksum  = (double*)  (ws + o); o += 2048 * 8;
    if (o > ws_size) return;

    hipMemsetAsync(chunkcnt, 0, (size_t)NCHUNK * 16 * 4, stream);
    hipMemsetAsync(ovcnt, 0, 64, stream);
    hipMemsetAsync(rowbest, 0xFF, (size_t)NROWS * 8, stream);     // ~0ull

    k_cbchain<<<dim3(256),  dim3(256), 0, stream>>>(emb, proj, cbf, cbh);
    k_zrow<<<dim3(1024), dim3(256), 0, stream>>>(z, zrow, zf, Arow);
    k_screen3<<<dim3(512), dim3(256), 0, stream>>>(zf, cbh, pmaxT);
    k_flag<<<dim3(NROWS / 256), dim3(256), 0, stream>>>(pmaxT, chunkcnt, chunkrows, ovcnt, ovlist);
    k_refine_bychunk<<<dim3(NCHUNK, 16), dim3(256), 0, stream>>>(zrow, cbf, Arow, chunkcnt, chunkrows, rowbest);
    k_refine_ov<<<dim3(64), dim3(256), 0, stream>>>(zrow, cbf, Arow, ovcnt, ovlist, rowbest);
    k_idx<<<dim3(NROWS / 256), dim3(256), 0, stream>>>(rowbest, zrow, cbf, Arow, idxw, out + 8388611);
    k_zq_mse<<<dim3(2048), dim3(256), 0, stream>>>(zrow, cbf, idxw, out, blocksum);
    k_final<<<dim3(1), dim3(256), 0, stream>>>(blocksum, out + 8388608);
}

// Round 13
// 584.322 us; speedup vs baseline: 3.6353x; 1.1282x over previous
//
#include <hip/hip_runtime.h>
#include <hip/hip_bf16.h>
#include <stdint.h>

#define B_ 32
#define H_ 32
#define W_ 32
#define NE 8192
#define NROWS 32768
#define K_ 256

#define MARGIN 4.0e-4f
#define NCHUNK 256          // 32-j chunks
#define MAXPER 8192
#define OVCAP (256 * 1024)

typedef unsigned short u16;
typedef unsigned long long u64;
typedef __attribute__((ext_vector_type(8))) short short8;
typedef __attribute__((ext_vector_type(4))) float f32x4;
typedef __attribute__((ext_vector_type(4))) unsigned short us4;

__device__ __forceinline__ u16 f2bf(float f) {
    union { float f; uint32_t u; } v; v.f = f;
    uint32_t u = v.u;
    uint32_t r = (u + 0x7fffu + ((u >> 16) & 1u)) >> 16;
    return (u16)r;
}

__device__ __forceinline__ unsigned fenc(float f) {
    unsigned b = __float_as_uint(f);
    return (b & 0x80000000u) ? ~b : (b | 0x80000000u);
}
__device__ __forceinline__ float fdec(unsigned e) {
    return (e & 0x80000000u) ? __uint_as_float(e & 0x7fffffffu) : __uint_as_float(~e);
}
// monotone u16 upper-bound encoding (round-up in fenc domain) — r9-proven
__device__ __forceinline__ u16 enc16ub(float f) {
    unsigned e = fenc(f);
    return (u16)((e >> 16) + ((e & 0xFFFFu) ? 1u : 0u));
}

// DPP row_ror rotate step (VALU pipe; rotates within 16-lane rows == our lr group) — r12-proven
template<int N>
__device__ __forceinline__ unsigned dpprorU(unsigned v) {
    return (unsigned)__builtin_amdgcn_mov_dpp((int)v, 0x120 + N, 0xf, 0xf, true);
}
// packed u16 max (VOP3P); max commutes with the monotone enc16ub
__device__ __forceinline__ unsigned pkmaxu(unsigned x, unsigned y) {
    unsigned d;
    asm("v_pk_max_u16 %0, %1, %2" : "=v"(d) : "v"(x), "v"(y));
    return d;
}

__device__ __forceinline__ void gload_lds16(const u16* g, u16* l) {
    __builtin_amdgcn_global_load_lds((const __attribute__((address_space(1))) void*)g,
                                     (__attribute__((address_space(3))) void*)l, 16, 0, 0);
}

// exact fp32 fma chain distance (k ascending, single accumulator) — verified r3 semantics
__device__ __forceinline__ float chain_d(const float* zp, const float* cp, float Ai) {
    float C = 0.0f;
    #pragma unroll 8
    for (int kq = 0; kq < 64; ++kq) {
        float4 zv = *(const float4*)&zp[kq * 4];
        float4 cv = *(const float4*)&cp[kq * 4];
        C = __builtin_fmaf(zv.x, cv.x, C);
        C = __builtin_fmaf(zv.y, cv.y, C);
        C = __builtin_fmaf(zv.z, cv.z, C);
        C = __builtin_fmaf(zv.w, cv.w, C);
    }
    return Ai - (C + C);
}

// ---- cb = emb @ proj^T : fp32 single-accumulator fma chain over k (BLAS replica) ----
// el via wave-uniform global float4 loads (L1-broadcast / s_load); proj row in 64 VGPRs.
__global__ __launch_bounds__(256, 2) void k_cbchain(const float* __restrict__ emb,
                                                    const float* __restrict__ proj,
                                                    float* __restrict__ cbf,
                                                    u16* __restrict__ cbh) {
    __shared__ float pl[256][65];
    const int t = threadIdx.x;      // output column (proj row)
    const int jb = blockIdx.x;      // 256 blocks x 32 codes
    float acc[32];
    #pragma unroll
    for (int j = 0; j < 32; ++j) acc[j] = 0.0f;
    for (int kc = 0; kc < 4; ++kc) {
        __syncthreads();
        for (int rep = 0; rep < 64; ++rep) {
            int idx = rep * 256 + t;
            int row = idx >> 6, k = idx & 63;
            pl[row][k] = proj[(size_t)row * 256 + kc * 64 + k];
        }
        __syncthreads();
        float4 pv[16];
        #pragma unroll
        for (int q = 0; q < 16; ++q) pv[q] = *(const float4*)&pl[t][q * 4];
        for (int k4 = 0; k4 < 16; ++k4) {
            float4 p = pv[k4];
            #pragma unroll
            for (int j = 0; j < 32; ++j) {
                float4 e = *(const float4*)&emb[(size_t)(jb * 32 + j) * 256 + kc * 64 + k4 * 4];
                float a = acc[j];
                a = __builtin_fmaf(e.x, p.x, a);   // k ascending, single chain
                a = __builtin_fmaf(e.y, p.y, a);
                a = __builtin_fmaf(e.z, p.z, a);
                a = __builtin_fmaf(e.w, p.w, a);
                acc[j] = a;
            }
        }
    }
    for (int j = 0; j < 32; ++j) {
        size_t off = (size_t)(jb * 32 + j) * 256 + t;
        cbf[off] = acc[j];
        cbh[off] = f2bf(acc[j]);
    }
}

// ---- z[b][c][h][w] -> zrow fp32 [n][c] + zf bf16 + A[n]=||z_n||^2 ----
__global__ __launch_bounds__(256) void k_zrow(const float* __restrict__ z,
                                              float* __restrict__ zrow,
                                              u16* __restrict__ zf,
                                              float* __restrict__ Arow) {
    int bh = blockIdx.x;          // 1024 = b*32+h
    int b = bh >> 5, h = bh & 31;
    __shared__ float tile[32][257];
    __shared__ double dsum[8][32];
    int t = threadIdx.x;
    int w = t & 31, cofs = t >> 5;
    double s = 0.0;
    for (int c0 = 0; c0 < 256; c0 += 8) {
        int c = c0 + cofs;
        float v = z[(((size_t)b * 256 + c) * H_ + h) * W_ + w];
        tile[w][c] = v;
        s = fma((double)v, (double)v, s);
    }
    dsum[cofs][w] = s;
    __syncthreads();
    int n0 = (b * H_ + h) * W_;
    if (t < 32) {
        double tot = 0.0;
        #pragma unroll
        for (int q = 0; q < 8; ++q) tot += dsum[q][t];
        Arow[n0 + t] = (float)tot;   // any representable fp32 works (tie-grid invariance, r3)
    }
    for (int rep = 0; rep < 8; ++rep) {
        int uid = rep * 256 + t;
        int ww = uid >> 6, u = uid & 63;
        float4 v;
        v.x = tile[ww][u * 4 + 0];
        v.y = tile[ww][u * 4 + 1];
        v.z = tile[ww][u * 4 + 2];
        v.w = tile[ww][u * 4 + 3];
        *(float4*)&zrow[((size_t)(n0 + ww)) * 256 + u * 4] = v;
        us4 bv;
        bv.x = f2bf(v.x); bv.y = f2bf(v.y); bv.z = f2bf(v.z); bv.w = f2bf(v.w);
        *(us4*)&zf[((size_t)(n0 + ww)) * 256 + u * 4] = bv;
    }
}

// ---- full-K screen GEMM: A in registers, B full-K LDS double-buffer, 1 barrier/tile ----
// Epilogue: enc16ub first (monotone), pack pairs, DPP + v_pk_max_u16 reduce (VALU only).
__global__ __launch_bounds__(256) void k_screen3(const u16* __restrict__ zf,
                                                 const u16* __restrict__ cbh,
                                                 u16* __restrict__ pmaxT) {
    __shared__ u16 Bs[2][64 * 256];   // 2 x 32 KB
    const int t = threadIdx.x;
    const int wid = t >> 6, lane = t & 63;
    const int lr = lane & 15, lg = lane >> 4;
    const int bm = blockIdx.x >> 1;
    const int g = blockIdx.x & 1;
    const int wr = wid >> 1, wc = wid & 1;
    const int wrow = bm * 128 + wr * 64;

    // A fragments: rows wrow + m*16 + lr, full K, straight from zf (one-time)
    short8 a[4][8];
    #pragma unroll
    for (int m = 0; m < 4; ++m) {
        const u16* zp = zf + (size_t)(wrow + m * 16 + lr) * 256 + lg * 8;
        #pragma unroll
        for (int ks = 0; ks < 8; ++ks)
            a[m][ks] = *(const short8*)&zp[ks * 32];
    }

    // staging source offsets (u16 units; row/unit XOR pre-swizzle, rule 21)
    int soff[8];
    #pragma unroll
    for (int s = 0; s < 8; ++s) {
        int c = s * 4 + wid;
        int row = c * 2 + (lane >> 5);
        int ug = (lane & 31) ^ (row & 7);
        soff[s] = row * 256 + ug * 8;
    }

    // b-frag LDS read addresses (swizzled), loop-invariant per lane
    const int rowb0 = wc * 32 + lr;
    const int rowb1 = rowb0 + 16;
    int baddr0[8], baddr1[8];
    #pragma unroll
    for (int ks = 0; ks < 8; ++ks) {
        baddr0[ks] = rowb0 * 256 + (((ks * 4 + lg) ^ (rowb0 & 7)) * 8);
        baddr1[ks] = rowb1 * 256 + (((ks * 4 + lg) ^ (rowb1 & 7)) * 8);
    }

    auto stage = [&](int buf, int tile) {
        const u16* base = cbh + (size_t)(g * 4096 + tile * 64) * 256;
        #pragma unroll
        for (int s = 0; s < 8; ++s)
            gload_lds16(base + soff[s], &Bs[buf][(s * 4 + wid) * 512]);
    };

    stage(0, 0);
    __syncthreads();
    int cur = 0;
    for (int tile = 0; tile < 64; ++tile) {
        if (tile < 63) stage(cur ^ 1, tile + 1);
        f32x4 acc[4][2] = {};
        #pragma unroll
        for (int ks = 0; ks < 8; ++ks) {
            short8 b0 = *(const short8*)&Bs[cur][baddr0[ks]];
            short8 b1 = *(const short8*)&Bs[cur][baddr1[ks]];
            #pragma unroll
            for (int m = 0; m < 4; ++m) {
                acc[m][0] = __builtin_amdgcn_mfma_f32_16x16x32_bf16(a[m][ks], b0, acc[m][0], 0, 0, 0);
                acc[m][1] = __builtin_amdgcn_mfma_f32_16x16x32_bf16(a[m][ks], b1, acc[m][1], 0, 0, 0);
            }
        }
        int chunk = g * 128 + tile * 2 + wc;
        #pragma unroll
        for (int m = 0; m < 4; ++m) {
            unsigned e01 = (unsigned)enc16ub(fmaxf(acc[m][0][0], acc[m][1][0]))
                         | ((unsigned)enc16ub(fmaxf(acc[m][0][1], acc[m][1][1])) << 16);
            unsigned e23 = (unsigned)enc16ub(fmaxf(acc[m][0][2], acc[m][1][2]))
                         | ((unsigned)enc16ub(fmaxf(acc[m][0][3], acc[m][1][3])) << 16);
            e01 = pkmaxu(e01, dpprorU<1>(e01));  e23 = pkmaxu(e23, dpprorU<1>(e23));
            e01 = pkmaxu(e01, dpprorU<2>(e01));  e23 = pkmaxu(e23, dpprorU<2>(e23));
            e01 = pkmaxu(e01, dpprorU<4>(e01));  e23 = pkmaxu(e23, dpprorU<4>(e23));
            e01 = pkmaxu(e01, dpprorU<8>(e01));  e23 = pkmaxu(e23, dpprorU<8>(e23));
            if (lr == 0) {
                us4 pack;
                pack.x = (u16)(e01 & 0xFFFFu); pack.y = (u16)(e01 >> 16);
                pack.z = (u16)(e23 & 0xFFFFu); pack.w = (u16)(e23 >> 16);
                *(us4*)&pmaxT[(size_t)chunk * NROWS + wrow + m * 16 + lg * 4] = pack;
            }
        }
        __syncthreads();
        cur ^= 1;
    }
}

// ---- rowmax + flag chunks >= thr; per-block LDS histogram kills hot-chunk atomic chains ----
__global__ __launch_bounds__(256) void k_flag(const u16* __restrict__ pmaxT,
                                              int* __restrict__ chunkcnt,     // stride 16 (pad)
                                              int* __restrict__ chunkrows,
                                              int* __restrict__ ovcnt,
                                              unsigned* __restrict__ ovlist) {
    __shared__ int lcnt[256];
    __shared__ int lslot[256];
    __shared__ int lbase[256];
    const int t = threadIdx.x;
    const int row = blockIdx.x * 256 + t;   // 128 blocks
    lcnt[t] = 0;
    lslot[t] = 0;

    float rm = -3.0e38f;
    for (int c = 0; c < NCHUNK; ++c)
        rm = fmaxf(rm, fdec((unsigned)pmaxT[(size_t)c * NROWS + row] << 16));
    const float thr = rm - MARGIN;

    u64 fl[4] = {0, 0, 0, 0};
    __syncthreads();
    for (int c = 0; c < NCHUNK; ++c) {
        float f = fdec((unsigned)pmaxT[(size_t)c * NROWS + row] << 16);
        if (f >= thr) {
            fl[c >> 6] |= 1ull << (c & 63);
            atomicAdd(&lcnt[c], 1);
        }
    }
    __syncthreads();
    {
        int myc = lcnt[t];
        lbase[t] = myc > 0 ? atomicAdd(&chunkcnt[t * 16], myc) : 0;
    }
    __syncthreads();
    for (int c = 0; c < NCHUNK; ++c) {
        if ((fl[c >> 6] >> (c & 63)) & 1) {
            int loc = atomicAdd(&lslot[c], 1);
            int slot = lbase[c] + loc;
            if (slot < MAXPER) {
                chunkrows[c * MAXPER + slot] = row;
            } else {
                int op = atomicAdd(ovcnt, 1);
                if (op < OVCAP) ovlist[op] = (unsigned)(row * NCHUNK + c);
            }
        }
    }
}

// ---- refine by chunk: stage 32 codes of cbf in LDS once, reuse across bucket rows ----
__global__ __launch_bounds__(256) void k_refine_bychunk(const float* __restrict__ zrow,
                                                        const float* __restrict__ cbf,
                                                        const float* __restrict__ Arow,
                                                        const int* __restrict__ chunkcnt,
                                                        const int* __restrict__ chunkrows,
                                                        u64* __restrict__ rowbest) {
    const int c = blockIdx.x;                    // chunk 0..255
    int cnt = chunkcnt[c * 16];
    if (cnt > MAXPER) cnt = MAXPER;
    if (cnt == 0) return;
    __shared__ float cl[32][260];                // +4 pad: conflict-free b128 column reads
    const int t = threadIdx.x;
    for (int u = t; u < 32 * 64; u += 256) {
        int code = u >> 6, kq = u & 63;
        *(float4*)&cl[code][kq * 4] = *(const float4*)&cbf[(size_t)(c * 32 + code) * 256 + kq * 4];
    }
    __syncthreads();
    const int wid = t >> 6, lane = t & 63;
    const int rsub = lane >> 4, lq = lane & 15;

    for (int i0 = blockIdx.y * 16 + wid * 4; i0 < cnt; i0 += 256) {
        int i = i0 + rsub;
        bool valid = i < cnt;
        int row = chunkrows[c * MAXPER + (valid ? i : 0)];
        const float* zp = zrow + (size_t)row * 256;
        float Ai = Arow[row];
        float C0 = 0.0f, C1 = 0.0f;
        #pragma unroll 8
        for (int kq = 0; kq < 64; ++kq) {
            float4 zv = *(const float4*)&zp[kq * 4];          // 16-lane broadcast
            float4 c0 = *(const float4*)&cl[lq][kq * 4];
            float4 c1 = *(const float4*)&cl[lq + 16][kq * 4];
            C0 = __builtin_fmaf(zv.x, c0.x, C0); C1 = __builtin_fmaf(zv.x, c1.x, C1);
            C0 = __builtin_fmaf(zv.y, c0.y, C0); C1 = __builtin_fmaf(zv.y, c1.y, C1);
            C0 = __builtin_fmaf(zv.z, c0.z, C0); C1 = __builtin_fmaf(zv.z, c1.z, C1);
            C0 = __builtin_fmaf(zv.w, c0.w, C0); C1 = __builtin_fmaf(zv.w, c1.w, C1);
        }
        float d0 = Ai - (C0 + C0);
        float d1 = Ai - (C1 + C1);
        int j0 = c * 32 + lq, j1 = j0 + 16;
        u64 k0 = ((u64)__float_as_uint(d0) << 32) | (unsigned)j0;
        u64 k1 = ((u64)__float_as_uint(d1) << 32) | (unsigned)j1;
        u64 key = k0 < k1 ? k0 : k1;
        if (!valid) key = ~0ull;
        #pragma unroll
        for (int mk = 1; mk < 16; mk <<= 1) {
            u64 o = __shfl_xor(key, mk, 64);
            if (o < key) key = o;
        }
        if (lq == 0 && valid) atomicMin(&rowbest[row], key);
    }
}

// ---- overflow refine (exact; expected never taken at MAXPER=8192) ----
__global__ __launch_bounds__(256) void k_refine_ov(const float* __restrict__ zrow,
                                                   const float* __restrict__ cbf,
                                                   const float* __restrict__ Arow,
                                                   const int* __restrict__ ovcnt,
                                                   const unsigned* __restrict__ ovlist,
                                                   u64* __restrict__ rowbest) {
    int total = *ovcnt;
    if (total > OVCAP) total = OVCAP;
    for (int p = blockIdx.x * 256 + threadIdx.x; p < total; p += gridDim.x * 256) {
        unsigned e = ovlist[p];
        int row = e / NCHUNK, chunk = e % NCHUNK;
        const float* zp = zrow + (size_t)row * 256;
        float Ai = Arow[row];
        u64 best = ~0ull;
        for (int q = 0; q < 32; ++q) {
            int j = chunk * 32 + q;
            float d = chain_d(zp, cbf + (size_t)j * 256, Ai);
            u64 key = ((u64)__float_as_uint(d) << 32) | (unsigned)j;
            if (key < best) best = key;
        }
        atomicMin(&rowbest[row], best);
    }
}

// ---- emit indices (never-taken exact full-scan fallback) ----
__global__ __launch_bounds__(256) void k_idx(const u64* __restrict__ rowbest,
                                             const float* __restrict__ zrow,
                                             const float* __restrict__ cbf,
                                             const float* __restrict__ Arow,
                                             int* __restrict__ idxw,
                                             float* __restrict__ idxf) {
    int row = blockIdx.x * 256 + threadIdx.x;   // 128 blocks
    u64 k = rowbest[row];
    int j;
    if (k != ~0ull) {
        j = (int)(k & 0xffffffffu);
    } else {
        u64 best = ~0ull;
        for (int jj = 0; jj < NE; ++jj) {
            float d = chain_d(zrow + (size_t)row * 256, cbf + (size_t)jj * 256, Arow[row]);
            u64 key = ((u64)__float_as_uint(d) << 32) | (unsigned)jj;
            if (key < best) best = key;
        }
        j = (int)(best & 0xffffffffu);
    }
    idxw[row] = j;
    idxf[row] = (float)j;
}

// ---- zq gather + fused MSE: 32 rows/block -> full 128B line writes per thread ----
__global__ __launch_bounds__(256) void k_zq_mse(const float* __restrict__ zrow,
                                                const float* __restrict__ cbf,
                                                const int* __restrict__ idxw,
                                                float* __restrict__ zq,
                                                double* __restrict__ blocksum) {
    const int t = threadIdx.x;
    const int n0 = blockIdx.x * 32;             // 1024 blocks
    double loc = 0.0;
    #pragma unroll 4
    for (int i = 0; i < 32; ++i) {
        int n = n0 + i;
        int j = idxw[n];                               // wave-uniform
        float q = cbf[(size_t)j * 256 + t];            // coalesced 1KB
        float zv = zrow[(size_t)n * 256 + t];          // coalesced 1KB (bit-copy of z)
        int b = n >> 10, h = (n >> 5) & 31, w = n & 31;
        zq[(((size_t)b * 256 + t) * 32 + h) * 32 + w] = q;   // thread fills its full 128B line
        double d = (double)q - (double)zv;
        loc += d * d;
    }
    #pragma unroll
    for (int mk = 1; mk < 64; mk <<= 1) loc += __shfl_xor(loc, mk, 64);
    __shared__ double wsum[4];
    int lane = t & 63, wid = t >> 6;
    if (lane == 0) wsum[wid] = loc;
    __syncthreads();
    if (t == 0) blocksum[blockIdx.x] = wsum[0] + wsum[1] + wsum[2] + wsum[3];
}

// ---- finalize scalars (sums 1024 block partials) ----
__global__ __launch_bounds__(256) void k_final(const double* __restrict__ blocksum,
                                               float* __restrict__ outs) {
    __shared__ double sh[4];
    int t = threadIdx.x;
    double s = 0.0;
    for (int i = t; i < 1024; i += 256) s += blocksum[i];
    #pragma unroll
    for (int mk = 1; mk < 64; mk <<= 1) s += __shfl_xor(s, mk, 64);
    int lane = t & 63, wid = t >> 6;
    if (lane == 0) sh[wid] = s;
    __syncthreads();
    if (t == 0) {
        double mse = (sh[0] + sh[1] + sh[2] + sh[3]) / (double)(32.0 * 256.0 * 32.0 * 32.0);
        outs[0] = (float)(1.25 * mse);   // loss
        outs[1] = (float)(0.25 * mse);   // commitment_loss
        outs[2] = (float)mse;            // codebook_loss
    }
}

extern "C" void kernel_launch(void* const* d_in, const int* in_sizes, int n_in,
                              void* d_out, int out_size, void* d_ws, size_t ws_size,
                              hipStream_t stream) {
    const float* z    = (const float*)d_in[0];
    const float* emb  = (const float*)d_in[1];
    const float* proj = (const float*)d_in[2];
    float* out = (float*)d_out;

    char* ws = (char*)d_ws;
    size_t o = 0;
    float*    cbf       = (float*)   (ws + o); o += (size_t)NE * 256 * 4;        // 8 MB
    u16*      cbh       = (u16*)     (ws + o); o += (size_t)NE * 256 * 2;        // 4 MB
    float*    zrow      = (float*)   (ws + o); o += (size_t)NROWS * 256 * 4;     // 32 MB
    u16*      zf        = (u16*)     (ws + o); o += (size_t)NROWS * 256 * 2;     // 16 MB
    float*    Arow      = (float*)   (ws + o); o += (size_t)NROWS * 4;
    u16*      pmaxT     = (u16*)     (ws + o); o += (size_t)NCHUNK * NROWS * 2;  // 16 MB
    int*      chunkcnt  = (int*)     (ws + o); o += (size_t)NCHUNK * 16 * 4;     // padded
    int*      chunkrows = (int*)     (ws + o); o += (size_t)NCHUNK * MAXPER * 4; // 8 MB
    int*      ovcnt     = (int*)     (ws + o); o += 64;
    unsigned* ovlist    = (unsigned*)(ws + o); o += (size_t)OVCAP * 4;           // 1 MB
    u64*      rowbest   = (u64*)     (ws + o); o += (size_t)NROWS * 8;           // 256 KB
    int*      idxw      = (int*)     (ws + o); o += (size_t)NROWS * 4;
    double*   blocksum  = (double*)  (ws + o); o += 1024 * 8;
    if (o > ws_size) return;

    hipMemsetAsync(chunkcnt, 0, (size_t)NCHUNK * 16 * 4, stream);
    hipMemsetAsync(ovcnt, 0, 64, stream);
    hipMemsetAsync(rowbest, 0xFF, (size_t)NROWS * 8, stream);     // ~0ull

    k_cbchain<<<dim3(256),  dim3(256), 0, stream>>>(emb, proj, cbf, cbh);
    k_zrow<<<dim3(1024), dim3(256), 0, stream>>>(z, zrow, zf, Arow);
    k_screen3<<<dim3(512), dim3(256), 0, stream>>>(zf, cbh, pmaxT);
    k_flag<<<dim3(NROWS / 256), dim3(256), 0, stream>>>(pmaxT, chunkcnt, chunkrows, ovcnt, ovlist);
    k_refine_bychunk<<<dim3(NCHUNK, 16), dim3(256), 0, stream>>>(zrow, cbf, Arow, chunkcnt, chunkrows, rowbest);
    k_refine_ov<<<dim3(64), dim3(256), 0, stream>>>(zrow, cbf, Arow, ovcnt, ovlist, rowbest);
    k_idx<<<dim3(NROWS / 256), dim3(256), 0, stream>>>(rowbest, zrow, cbf, Arow, idxw, out + 8388611);
    k_zq_mse<<<dim3(1024), dim3(256), 0, stream>>>(zrow, cbf, idxw, out, blocksum);
    k_final<<<dim3(1), dim3(256), 0, stream>>>(blocksum, out + 8388608);
}

// Round 14
// 474.707 us; speedup vs baseline: 4.4748x; 1.2309x over previous
//
#include <hip/hip_runtime.h>
#include <hip/hip_bf16.h>
#include <stdint.h>

#define B_ 32
#define H_ 32
#define W_ 32
#define NE 8192
#define NROWS 32768
#define K_ 256

#define MARGIN 4.0e-4f
#define NCHUNK 256          // 32-j chunks
#define MAXPER 8192
#define OVCAP (256 * 1024)

typedef unsigned short u16;
typedef unsigned long long u64;
typedef __attribute__((ext_vector_type(8))) short short8;
typedef __attribute__((ext_vector_type(4))) float f32x4;
typedef __attribute__((ext_vector_type(4))) unsigned short us4;

__device__ __forceinline__ u16 f2bf(float f) {
    union { float f; uint32_t u; } v; v.f = f;
    uint32_t u = v.u;
    uint32_t r = (u + 0x7fffu + ((u >> 16) & 1u)) >> 16;
    return (u16)r;
}

__device__ __forceinline__ unsigned fenc(float f) {
    unsigned b = __float_as_uint(f);
    return (b & 0x80000000u) ? ~b : (b | 0x80000000u);
}
__device__ __forceinline__ float fdec(unsigned e) {
    return (e & 0x80000000u) ? __uint_as_float(e & 0x7fffffffu) : __uint_as_float(~e);
}
// monotone u16 upper-bound encoding (round-up in fenc domain) — r9-proven
__device__ __forceinline__ u16 enc16ub(float f) {
    unsigned e = fenc(f);
    return (u16)((e >> 16) + ((e & 0xFFFFu) ? 1u : 0u));
}

// DPP row_ror rotate step (VALU pipe; rotates within 16-lane rows == our lr group) — r12-proven
template<int N>
__device__ __forceinline__ unsigned dpprorU(unsigned v) {
    return (unsigned)__builtin_amdgcn_mov_dpp((int)v, 0x120 + N, 0xf, 0xf, true);
}
// packed u16 max (VOP3P); max commutes with the monotone enc16ub
__device__ __forceinline__ unsigned pkmaxu(unsigned x, unsigned y) {
    unsigned d;
    asm("v_pk_max_u16 %0, %1, %2" : "=v"(d) : "v"(x), "v"(y));
    return d;
}

__device__ __forceinline__ void gload_lds16(const u16* g, u16* l) {
    __builtin_amdgcn_global_load_lds((const __attribute__((address_space(1))) void*)g,
                                     (__attribute__((address_space(3))) void*)l, 16, 0, 0);
}

// exact fp32 fma chain distance (k ascending, single accumulator) — verified r3 semantics
__device__ __forceinline__ float chain_d(const float* zp, const float* cp, float Ai) {
    float C = 0.0f;
    #pragma unroll 8
    for (int kq = 0; kq < 64; ++kq) {
        float4 zv = *(const float4*)&zp[kq * 4];
        float4 cv = *(const float4*)&cp[kq * 4];
        C = __builtin_fmaf(zv.x, cv.x, C);
        C = __builtin_fmaf(zv.y, cv.y, C);
        C = __builtin_fmaf(zv.z, cv.z, C);
        C = __builtin_fmaf(zv.w, cv.w, C);
    }
    return Ai - (C + C);
}

// ---- cb = emb @ proj^T : fp32 single-accumulator fma chain over k (BLAS replica) ----
// v3: 1024 blocks x 8 codes; proj staged in 32-k chunks (33.8KB LDS -> 4 blocks/CU, 16 waves/CU).
// Chain bit-identical: k ascending 0..255, one fmaf accumulator per output.
__global__ __launch_bounds__(256) void k_cbchain(const float* __restrict__ emb,
                                                 const float* __restrict__ proj,
                                                 float* __restrict__ cbf,
                                                 u16* __restrict__ cbh) {
    __shared__ float pl[256][33];   // stride 33: conflict-free b32 column reads
    const int t = threadIdx.x;      // output column (proj row)
    const int jb = blockIdx.x;      // 1024 blocks x 8 codes
    float acc[8];
    #pragma unroll
    for (int j = 0; j < 8; ++j) acc[j] = 0.0f;

    for (int kc = 0; kc < 8; ++kc) {          // 8 phases of 32 k
        __syncthreads();
        #pragma unroll
        for (int rep = 0; rep < 8; ++rep) {   // stage 256x32 floats, coalesced float4
            int gidx = rep * 1024 + t * 4;
            int row = gidx >> 5, k = gidx & 31;
            float4 v = *(const float4*)&proj[(size_t)row * 256 + kc * 32 + k];
            pl[row][k + 0] = v.x; pl[row][k + 1] = v.y;
            pl[row][k + 2] = v.z; pl[row][k + 3] = v.w;
        }
        __syncthreads();
        float p[32];
        #pragma unroll
        for (int q = 0; q < 32; ++q) p[q] = pl[t][q];
        #pragma unroll
        for (int k4 = 0; k4 < 8; ++k4) {
            #pragma unroll
            for (int j = 0; j < 8; ++j) {
                float4 e = *(const float4*)&emb[(size_t)(jb * 8 + j) * 256 + kc * 32 + k4 * 4];
                float a = acc[j];
                a = __builtin_fmaf(e.x, p[k4 * 4 + 0], a);   // k ascending, single chain
                a = __builtin_fmaf(e.y, p[k4 * 4 + 1], a);
                a = __builtin_fmaf(e.z, p[k4 * 4 + 2], a);
                a = __builtin_fmaf(e.w, p[k4 * 4 + 3], a);
                acc[j] = a;
            }
        }
    }
    #pragma unroll
    for (int j = 0; j < 8; ++j) {
        size_t off = (size_t)(jb * 8 + j) * 256 + t;
        cbf[off] = acc[j];
        cbh[off] = f2bf(acc[j]);
    }
}

// ---- z[b][c][h][w] -> zrow fp32 [n][c] + zf bf16 + A[n]=||z_n||^2 ----
__global__ __launch_bounds__(256) void k_zrow(const float* __restrict__ z,
                                              float* __restrict__ zrow,
                                              u16* __restrict__ zf,
                                              float* __restrict__ Arow) {
    int bh = blockIdx.x;          // 1024 = b*32+h
    int b = bh >> 5, h = bh & 31;
    __shared__ float tile[32][257];
    __shared__ double dsum[8][32];
    int t = threadIdx.x;
    int w = t & 31, cofs = t >> 5;
    double s = 0.0;
    for (int c0 = 0; c0 < 256; c0 += 8) {
        int c = c0 + cofs;
        float v = z[(((size_t)b * 256 + c) * H_ + h) * W_ + w];
        tile[w][c] = v;
        s = fma((double)v, (double)v, s);
    }
    dsum[cofs][w] = s;
    __syncthreads();
    int n0 = (b * H_ + h) * W_;
    if (t < 32) {
        double tot = 0.0;
        #pragma unroll
        for (int q = 0; q < 8; ++q) tot += dsum[q][t];
        Arow[n0 + t] = (float)tot;   // any representable fp32 works (tie-grid invariance, r3)
    }
    for (int rep = 0; rep < 8; ++rep) {
        int uid = rep * 256 + t;
        int ww = uid >> 6, u = uid & 63;
        float4 v;
        v.x = tile[ww][u * 4 + 0];
        v.y = tile[ww][u * 4 + 1];
        v.z = tile[ww][u * 4 + 2];
        v.w = tile[ww][u * 4 + 3];
        *(float4*)&zrow[((size_t)(n0 + ww)) * 256 + u * 4] = v;
        us4 bv;
        bv.x = f2bf(v.x); bv.y = f2bf(v.y); bv.z = f2bf(v.z); bv.w = f2bf(v.w);
        *(us4*)&zf[((size_t)(n0 + ww)) * 256 + u * 4] = bv;
    }
}

// ---- full-K screen GEMM: A in registers, B full-K LDS double-buffer, 1 barrier/tile ----
// Epilogue: enc16ub first (monotone), pack pairs, DPP + v_pk_max_u16 reduce (VALU only).
__global__ __launch_bounds__(256) void k_screen3(const u16* __restrict__ zf,
                                                 const u16* __restrict__ cbh,
                                                 u16* __restrict__ pmaxT) {
    __shared__ u16 Bs[2][64 * 256];   // 2 x 32 KB
    const int t = threadIdx.x;
    const int wid = t >> 6, lane = t & 63;
    const int lr = lane & 15, lg = lane >> 4;
    const int bm = blockIdx.x >> 1;
    const int g = blockIdx.x & 1;
    const int wr = wid >> 1, wc = wid & 1;
    const int wrow = bm * 128 + wr * 64;

    // A fragments: rows wrow + m*16 + lr, full K, straight from zf (one-time)
    short8 a[4][8];
    #pragma unroll
    for (int m = 0; m < 4; ++m) {
        const u16* zp = zf + (size_t)(wrow + m * 16 + lr) * 256 + lg * 8;
        #pragma unroll
        for (int ks = 0; ks < 8; ++ks)
            a[m][ks] = *(const short8*)&zp[ks * 32];
    }

    // staging source offsets (u16 units; row/unit XOR pre-swizzle, rule 21)
    int soff[8];
    #pragma unroll
    for (int s = 0; s < 8; ++s) {
        int c = s * 4 + wid;
        int row = c * 2 + (lane >> 5);
        int ug = (lane & 31) ^ (row & 7);
        soff[s] = row * 256 + ug * 8;
    }

    // b-frag LDS read addresses (swizzled), loop-invariant per lane
    const int rowb0 = wc * 32 + lr;
    const int rowb1 = rowb0 + 16;
    int baddr0[8], baddr1[8];
    #pragma unroll
    for (int ks = 0; ks < 8; ++ks) {
        baddr0[ks] = rowb0 * 256 + (((ks * 4 + lg) ^ (rowb0 & 7)) * 8);
        baddr1[ks] = rowb1 * 256 + (((ks * 4 + lg) ^ (rowb1 & 7)) * 8);
    }

    auto stage = [&](int buf, int tile) {
        const u16* base = cbh + (size_t)(g * 4096 + tile * 64) * 256;
        #pragma unroll
        for (int s = 0; s < 8; ++s)
            gload_lds16(base + soff[s], &Bs[buf][(s * 4 + wid) * 512]);
    };

    stage(0, 0);
    __syncthreads();
    int cur = 0;
    for (int tile = 0; tile < 64; ++tile) {
        if (tile < 63) stage(cur ^ 1, tile + 1);
        f32x4 acc[4][2] = {};
        #pragma unroll
        for (int ks = 0; ks < 8; ++ks) {
            short8 b0 = *(const short8*)&Bs[cur][baddr0[ks]];
            short8 b1 = *(const short8*)&Bs[cur][baddr1[ks]];
            #pragma unroll
            for (int m = 0; m < 4; ++m) {
                acc[m][0] = __builtin_amdgcn_mfma_f32_16x16x32_bf16(a[m][ks], b0, acc[m][0], 0, 0, 0);
                acc[m][1] = __builtin_amdgcn_mfma_f32_16x16x32_bf16(a[m][ks], b1, acc[m][1], 0, 0, 0);
            }
        }
        int chunk = g * 128 + tile * 2 + wc;
        #pragma unroll
        for (int m = 0; m < 4; ++m) {
            unsigned e01 = (unsigned)enc16ub(fmaxf(acc[m][0][0], acc[m][1][0]))
                         | ((unsigned)enc16ub(fmaxf(acc[m][0][1], acc[m][1][1])) << 16);
            unsigned e23 = (unsigned)enc16ub(fmaxf(acc[m][0][2], acc[m][1][2]))
                         | ((unsigned)enc16ub(fmaxf(acc[m][0][3], acc[m][1][3])) << 16);
            e01 = pkmaxu(e01, dpprorU<1>(e01));  e23 = pkmaxu(e23, dpprorU<1>(e23));
            e01 = pkmaxu(e01, dpprorU<2>(e01));  e23 = pkmaxu(e23, dpprorU<2>(e23));
            e01 = pkmaxu(e01, dpprorU<4>(e01));  e23 = pkmaxu(e23, dpprorU<4>(e23));
            e01 = pkmaxu(e01, dpprorU<8>(e01));  e23 = pkmaxu(e23, dpprorU<8>(e23));
            if (lr == 0) {
                us4 pack;
                pack.x = (u16)(e01 & 0xFFFFu); pack.y = (u16)(e01 >> 16);
                pack.z = (u16)(e23 & 0xFFFFu); pack.w = (u16)(e23 >> 16);
                *(us4*)&pmaxT[(size_t)chunk * NROWS + wrow + m * 16 + lg * 4] = pack;
            }
        }
        __syncthreads();
        cur ^= 1;
    }
}

// ---- rowmax + flag chunks >= thr; per-block LDS histogram kills hot-chunk atomic chains ----
__global__ __launch_bounds__(256) void k_flag(const u16* __restrict__ pmaxT,
                                              int* __restrict__ chunkcnt,     // stride 16 (pad)
                                              int* __restrict__ chunkrows,
                                              int* __restrict__ ovcnt,
                                              unsigned* __restrict__ ovlist) {
    __shared__ int lcnt[256];
    __shared__ int lslot[256];
    __shared__ int lbase[256];
    const int t = threadIdx.x;
    const int row = blockIdx.x * 256 + t;   // 128 blocks
    lcnt[t] = 0;
    lslot[t] = 0;

    float rm = -3.0e38f;
    for (int c = 0; c < NCHUNK; ++c)
        rm = fmaxf(rm, fdec((unsigned)pmaxT[(size_t)c * NROWS + row] << 16));
    const float thr = rm - MARGIN;

    u64 fl[4] = {0, 0, 0, 0};
    __syncthreads();
    for (int c = 0; c < NCHUNK; ++c) {
        float f = fdec((unsigned)pmaxT[(size_t)c * NROWS + row] << 16);
        if (f >= thr) {
            fl[c >> 6] |= 1ull << (c & 63);
            atomicAdd(&lcnt[c], 1);
        }
    }
    __syncthreads();
    {
        int myc = lcnt[t];
        lbase[t] = myc > 0 ? atomicAdd(&chunkcnt[t * 16], myc) : 0;
    }
    __syncthreads();
    for (int c = 0; c < NCHUNK; ++c) {
        if ((fl[c >> 6] >> (c & 63)) & 1) {
            int loc = atomicAdd(&lslot[c], 1);
            int slot = lbase[c] + loc;
            if (slot < MAXPER) {
                chunkrows[c * MAXPER + slot] = row;
            } else {
                int op = atomicAdd(ovcnt, 1);
                if (op < OVCAP) ovlist[op] = (unsigned)(row * NCHUNK + c);
            }
        }
    }
}

// ---- refine by chunk: stage 32 codes of cbf in LDS once, reuse across bucket rows ----
__global__ __launch_bounds__(256) void k_refine_bychunk(const float* __restrict__ zrow,
                                                        const float* __restrict__ cbf,
                                                        const float* __restrict__ Arow,
                                                        const int* __restrict__ chunkcnt,
                                                        const int* __restrict__ chunkrows,
                                                        u64* __restrict__ rowbest) {
    const int c = blockIdx.x;                    // chunk 0..255
    int cnt = chunkcnt[c * 16];
    if (cnt > MAXPER) cnt = MAXPER;
    if (cnt == 0) return;
    __shared__ float cl[32][260];                // +4 pad: conflict-free b128 column reads
    const int t = threadIdx.x;
    for (int u = t; u < 32 * 64; u += 256) {
        int code = u >> 6, kq = u & 63;
        *(float4*)&cl[code][kq * 4] = *(const float4*)&cbf[(size_t)(c * 32 + code) * 256 + kq * 4];
    }
    __syncthreads();
    const int wid = t >> 6, lane = t & 63;
    const int rsub = lane >> 4, lq = lane & 15;

    for (int i0 = blockIdx.y * 16 + wid * 4; i0 < cnt; i0 += 256) {
        int i = i0 + rsub;
        bool valid = i < cnt;
        int row = chunkrows[c * MAXPER + (valid ? i : 0)];
        const float* zp = zrow + (size_t)row * 256;
        float Ai = Arow[row];
        float C0 = 0.0f, C1 = 0.0f;
        #pragma unroll 8
        for (int kq = 0; kq < 64; ++kq) {
            float4 zv = *(const float4*)&zp[kq * 4];          // 16-lane broadcast
            float4 c0 = *(const float4*)&cl[lq][kq * 4];
            float4 c1 = *(const float4*)&cl[lq + 16][kq * 4];
            C0 = __builtin_fmaf(zv.x, c0.x, C0); C1 = __builtin_fmaf(zv.x, c1.x, C1);
            C0 = __builtin_fmaf(zv.y, c0.y, C0); C1 = __builtin_fmaf(zv.y, c1.y, C1);
            C0 = __builtin_fmaf(zv.z, c0.z, C0); C1 = __builtin_fmaf(zv.z, c1.z, C1);
            C0 = __builtin_fmaf(zv.w, c0.w, C0); C1 = __builtin_fmaf(zv.w, c1.w, C1);
        }
        float d0 = Ai - (C0 + C0);
        float d1 = Ai - (C1 + C1);
        int j0 = c * 32 + lq, j1 = j0 + 16;
        u64 k0 = ((u64)__float_as_uint(d0) << 32) | (unsigned)j0;
        u64 k1 = ((u64)__float_as_uint(d1) << 32) | (unsigned)j1;
        u64 key = k0 < k1 ? k0 : k1;
        if (!valid) key = ~0ull;
        #pragma unroll
        for (int mk = 1; mk < 16; mk <<= 1) {
            u64 o = __shfl_xor(key, mk, 64);
            if (o < key) key = o;
        }
        if (lq == 0 && valid) atomicMin(&rowbest[row], key);
    }
}

// ---- overflow refine (exact; expected never taken at MAXPER=8192) ----
__global__ __launch_bounds__(256) void k_refine_ov(const float* __restrict__ zrow,
                                                   const float* __restrict__ cbf,
                                                   const float* __restrict__ Arow,
                                                   const int* __restrict__ ovcnt,
                                                   const unsigned* __restrict__ ovlist,
                                                   u64* __restrict__ rowbest) {
    int total = *ovcnt;
    if (total > OVCAP) total = OVCAP;
    for (int p = blockIdx.x * 256 + threadIdx.x; p < total; p += gridDim.x * 256) {
        unsigned e = ovlist[p];
        int row = e / NCHUNK, chunk = e % NCHUNK;
        const float* zp = zrow + (size_t)row * 256;
        float Ai = Arow[row];
        u64 best = ~0ull;
        for (int q = 0; q < 32; ++q) {
            int j = chunk * 32 + q;
            float d = chain_d(zp, cbf + (size_t)j * 256, Ai);
            u64 key = ((u64)__float_as_uint(d) << 32) | (unsigned)j;
            if (key < best) best = key;
        }
        atomicMin(&rowbest[row], best);
    }
}

// ---- emit indices (never-taken exact full-scan fallback) ----
__global__ __launch_bounds__(256) void k_idx(const u64* __restrict__ rowbest,
                                             const float* __restrict__ zrow,
                                             const float* __restrict__ cbf,
                                             const float* __restrict__ Arow,
                                             int* __restrict__ idxw,
                                             float* __restrict__ idxf) {
    int row = blockIdx.x * 256 + threadIdx.x;   // 128 blocks
    u64 k = rowbest[row];
    int j;
    if (k != ~0ull) {
        j = (int)(k & 0xffffffffu);
    } else {
        u64 best = ~0ull;
        for (int jj = 0; jj < NE; ++jj) {
            float d = chain_d(zrow + (size_t)row * 256, cbf + (size_t)jj * 256, Arow[row]);
            u64 key = ((u64)__float_as_uint(d) << 32) | (unsigned)jj;
            if (key < best) best = key;
        }
        j = (int)(best & 0xffffffffu);
    }
    idxw[row] = j;
    idxf[row] = (float)j;
}

// ---- zq gather + fused MSE: 32 rows/block -> full 128B line writes per thread ----
__global__ __launch_bounds__(256) void k_zq_mse(const float* __restrict__ zrow,
                                                const float* __restrict__ cbf,
                                                const int* __restrict__ idxw,
                                                float* __restrict__ zq,
                                                double* __restrict__ blocksum) {
    const int t = threadIdx.x;
    const int n0 = blockIdx.x * 32;             // 1024 blocks
    double loc = 0.0;
    #pragma unroll 4
    for (int i = 0; i < 32; ++i) {
        int n = n0 + i;
        int j = idxw[n];                               // wave-uniform
        float q = cbf[(size_t)j * 256 + t];            // coalesced 1KB
        float zv = zrow[(size_t)n * 256 + t];          // coalesced 1KB (bit-copy of z)
        int b = n >> 10, h = (n >> 5) & 31, w = n & 31;
        zq[(((size_t)b * 256 + t) * 32 + h) * 32 + w] = q;   // thread fills its full 128B line
        double d = (double)q - (double)zv;
        loc += d * d;
    }
    #pragma unroll
    for (int mk = 1; mk < 64; mk <<= 1) loc += __shfl_xor(loc, mk, 64);
    __shared__ double wsum[4];
    int lane = t & 63, wid = t >> 6;
    if (lane == 0) wsum[wid] = loc;
    __syncthreads();
    if (t == 0) blocksum[blockIdx.x] = wsum[0] + wsum[1] + wsum[2] + wsum[3];
}

// ---- finalize scalars (sums 1024 block partials) ----
__global__ __launch_bounds__(256) void k_final(const double* __restrict__ blocksum,
                                               float* __restrict__ outs) {
    __shared__ double sh[4];
    int t = threadIdx.x;
    double s = 0.0;
    for (int i = t; i < 1024; i += 256) s += blocksum[i];
    #pragma unroll
    for (int mk = 1; mk < 64; mk <<= 1) s += __shfl_xor(s, mk, 64);
    int lane = t & 63, wid = t >> 6;
    if (lane == 0) sh[wid] = s;
    __syncthreads();
    if (t == 0) {
        double mse = (sh[0] + sh[1] + sh[2] + sh[3]) / (double)(32.0 * 256.0 * 32.0 * 32.0);
        outs[0] = (float)(1.25 * mse);   // loss
        outs[1] = (float)(0.25 * mse);   // commitment_loss
        outs[2] = (float)mse;            // codebook_loss
    }
}

extern "C" void kernel_launch(void* const* d_in, const int* in_sizes, int n_in,
                              void* d_out, int out_size, void* d_ws, size_t ws_size,
                              hipStream_t stream) {
    const float* z    = (const float*)d_in[0];
    const float* emb  = (const float*)d_in[1];
    const float* proj = (const float*)d_in[2];
    float* out = (float*)d_out;

    char* ws = (char*)d_ws;
    size_t o = 0;
    float*    cbf       = (float*)   (ws + o); o += (size_t)NE * 256 * 4;        // 8 MB
    u16*      cbh       = (u16*)     (ws + o); o += (size_t)NE * 256 * 2;        // 4 MB
    float*    zrow      = (float*)   (ws + o); o += (size_t)NROWS * 256 * 4;     // 32 MB
    u16*      zf        = (u16*)     (ws + o); o += (size_t)NROWS * 256 * 2;     // 16 MB
    float*    Arow      = (float*)   (ws + o); o += (size_t)NROWS * 4;
    u16*      pmaxT     = (u16*)     (ws + o); o += (size_t)NCHUNK * NROWS * 2;  // 16 MB
    int*      chunkcnt  = (int*)     (ws + o); o += (size_t)NCHUNK * 16 * 4;     // padded
    int*      chunkrows = (int*)     (ws + o); o += (size_t)NCHUNK * MAXPER * 4; // 8 MB
    int*      ovcnt     = (int*)     (ws + o); o += 64;
    unsigned* ovlist    = (unsigned*)(ws + o); o += (size_t)OVCAP * 4;           // 1 MB
    u64*      rowbest   = (u64*)     (ws + o); o += (size_t)NROWS * 8;           // 256 KB
    int*      idxw      = (int*)     (ws + o); o += (size_t)NROWS * 4;
    double*   blocksum  = (double*)  (ws + o); o += 1024 * 8;
    if (o > ws_size) return;

    hipMemsetAsync(chunkcnt, 0, (size_t)NCHUNK * 16 * 4, stream);
    hipMemsetAsync(ovcnt, 0, 64, stream);
    hipMemsetAsync(rowbest, 0xFF, (size_t)NROWS * 8, stream);     // ~0ull

    k_cbchain<<<dim3(1024), dim3(256), 0, stream>>>(emb, proj, cbf, cbh);
    k_zrow<<<dim3(1024), dim3(256), 0, stream>>>(z, zrow, zf, Arow);
    k_screen3<<<dim3(512), dim3(256), 0, stream>>>(zf, cbh, pmaxT);
    k_flag<<<dim3(NROWS / 256), dim3(256), 0, stream>>>(pmaxT, chunkcnt, chunkrows, ovcnt, ovlist);
    k_refine_bychunk<<<dim3(NCHUNK, 16), dim3(256), 0, stream>>>(zrow, cbf, Arow, chunkcnt, chunkrows, rowbest);
    k_refine_ov<<<dim3(64), dim3(256), 0, stream>>>(zrow, cbf, Arow, ovcnt, ovlist, rowbest);
    k_idx<<<dim3(NROWS / 256), dim3(256), 0, stream>>>(rowbest, zrow, cbf, Arow, idxw, out + 8388611);
    k_zq_mse<<<dim3(1024), dim3(256), 0, stream>>>(zrow, cbf, idxw, out, blocksum);
    k_final<<<dim3(1), dim3(256), 0, stream>>>(blocksum, out + 8388608);
}

// Round 15
// 467.238 us; speedup vs baseline: 4.5463x; 1.0160x over previous
//
#include <hip/hip_runtime.h>
#include <hip/hip_bf16.h>
#include <stdint.h>

#define B_ 32
#define H_ 32
#define W_ 32
#define NE 8192
#define NROWS 32768
#define K_ 256

#define MARGIN 4.0e-4f
#define NCHUNK 256          // 32-j chunks
#define MAXPER 8192
#define OVCAP (256 * 1024)

typedef unsigned short u16;
typedef unsigned long long u64;
typedef __attribute__((ext_vector_type(8))) short short8;
typedef __attribute__((ext_vector_type(4))) float f32x4;
typedef __attribute__((ext_vector_type(4))) unsigned short us4;

__device__ __forceinline__ u16 f2bf(float f) {
    union { float f; uint32_t u; } v; v.f = f;
    uint32_t u = v.u;
    uint32_t r = (u + 0x7fffu + ((u >> 16) & 1u)) >> 16;
    return (u16)r;
}

__device__ __forceinline__ unsigned fenc(float f) {
    unsigned b = __float_as_uint(f);
    return (b & 0x80000000u) ? ~b : (b | 0x80000000u);
}
__device__ __forceinline__ float fdec(unsigned e) {
    return (e & 0x80000000u) ? __uint_as_float(e & 0x7fffffffu) : __uint_as_float(~e);
}
// monotone u16 upper-bound encoding (round-up in fenc domain) — r9-proven
__device__ __forceinline__ u16 enc16ub(float f) {
    unsigned e = fenc(f);
    return (u16)((e >> 16) + ((e & 0xFFFFu) ? 1u : 0u));
}

// DPP row_ror rotate step (VALU pipe; rotates within 16-lane rows == our lr group) — r12-proven
template<int N>
__device__ __forceinline__ unsigned dpprorU(unsigned v) {
    return (unsigned)__builtin_amdgcn_mov_dpp((int)v, 0x120 + N, 0xf, 0xf, true);
}
// packed u16 max (VOP3P); max commutes with the monotone enc16ub
__device__ __forceinline__ unsigned pkmaxu(unsigned x, unsigned y) {
    unsigned d;
    asm("v_pk_max_u16 %0, %1, %2" : "=v"(d) : "v"(x), "v"(y));
    return d;
}

__device__ __forceinline__ void gload_lds16(const u16* g, u16* l) {
    __builtin_amdgcn_global_load_lds((const __attribute__((address_space(1))) void*)g,
                                     (__attribute__((address_space(3))) void*)l, 16, 0, 0);
}

// exact fp32 fma chain distance (k ascending, single accumulator) — verified r3 semantics
__device__ __forceinline__ float chain_d(const float* zp, const float* cp, float Ai) {
    float C = 0.0f;
    #pragma unroll 8
    for (int kq = 0; kq < 64; ++kq) {
        float4 zv = *(const float4*)&zp[kq * 4];
        float4 cv = *(const float4*)&cp[kq * 4];
        C = __builtin_fmaf(zv.x, cv.x, C);
        C = __builtin_fmaf(zv.y, cv.y, C);
        C = __builtin_fmaf(zv.z, cv.z, C);
        C = __builtin_fmaf(zv.w, cv.w, C);
    }
    return Ai - (C + C);
}

// ---- cb = emb @ proj^T : fp32 single-accumulator fma chain over k (BLAS replica) ----
__global__ __launch_bounds__(256) void k_cbchain(const float* __restrict__ emb,
                                                 const float* __restrict__ proj,
                                                 float* __restrict__ cbf,
                                                 u16* __restrict__ cbh) {
    __shared__ float pl[256][33];   // stride 33: conflict-free b32 column reads
    const int t = threadIdx.x;      // output column (proj row)
    const int jb = blockIdx.x;      // 1024 blocks x 8 codes
    float acc[8];
    #pragma unroll
    for (int j = 0; j < 8; ++j) acc[j] = 0.0f;

    for (int kc = 0; kc < 8; ++kc) {          // 8 phases of 32 k
        __syncthreads();
        #pragma unroll
        for (int rep = 0; rep < 8; ++rep) {   // stage 256x32 floats, coalesced float4
            int gidx = rep * 1024 + t * 4;
            int row = gidx >> 5, k = gidx & 31;
            float4 v = *(const float4*)&proj[(size_t)row * 256 + kc * 32 + k];
            pl[row][k + 0] = v.x; pl[row][k + 1] = v.y;
            pl[row][k + 2] = v.z; pl[row][k + 3] = v.w;
        }
        __syncthreads();
        float p[32];
        #pragma unroll
        for (int q = 0; q < 32; ++q) p[q] = pl[t][q];
        #pragma unroll
        for (int k4 = 0; k4 < 8; ++k4) {
            #pragma unroll
            for (int j = 0; j < 8; ++j) {
                float4 e = *(const float4*)&emb[(size_t)(jb * 8 + j) * 256 + kc * 32 + k4 * 4];
                float a = acc[j];
                a = __builtin_fmaf(e.x, p[k4 * 4 + 0], a);   // k ascending, single chain
                a = __builtin_fmaf(e.y, p[k4 * 4 + 1], a);
                a = __builtin_fmaf(e.z, p[k4 * 4 + 2], a);
                a = __builtin_fmaf(e.w, p[k4 * 4 + 3], a);
                acc[j] = a;
            }
        }
    }
    #pragma unroll
    for (int j = 0; j < 8; ++j) {
        size_t off = (size_t)(jb * 8 + j) * 256 + t;
        cbf[off] = acc[j];
        cbh[off] = f2bf(acc[j]);
    }
}

// ---- z[b][c][h][w] -> zrow fp32 [n][c] + zf bf16 + A[n]=||z_n||^2 ----
__global__ __launch_bounds__(256) void k_zrow(const float* __restrict__ z,
                                              float* __restrict__ zrow,
                                              u16* __restrict__ zf,
                                              float* __restrict__ Arow) {
    int bh = blockIdx.x;          // 1024 = b*32+h
    int b = bh >> 5, h = bh & 31;
    __shared__ float tile[32][257];
    __shared__ double dsum[8][32];
    int t = threadIdx.x;
    int w = t & 31, cofs = t >> 5;
    double s = 0.0;
    for (int c0 = 0; c0 < 256; c0 += 8) {
        int c = c0 + cofs;
        float v = z[(((size_t)b * 256 + c) * H_ + h) * W_ + w];
        tile[w][c] = v;
        s = fma((double)v, (double)v, s);
    }
    dsum[cofs][w] = s;
    __syncthreads();
    int n0 = (b * H_ + h) * W_;
    if (t < 32) {
        double tot = 0.0;
        #pragma unroll
        for (int q = 0; q < 8; ++q) tot += dsum[q][t];
        Arow[n0 + t] = (float)tot;   // any representable fp32 works (tie-grid invariance, r3)
    }
    for (int rep = 0; rep < 8; ++rep) {
        int uid = rep * 256 + t;
        int ww = uid >> 6, u = uid & 63;
        float4 v;
        v.x = tile[ww][u * 4 + 0];
        v.y = tile[ww][u * 4 + 1];
        v.z = tile[ww][u * 4 + 2];
        v.w = tile[ww][u * 4 + 3];
        *(float4*)&zrow[((size_t)(n0 + ww)) * 256 + u * 4] = v;
        us4 bv;
        bv.x = f2bf(v.x); bv.y = f2bf(v.y); bv.z = f2bf(v.z); bv.w = f2bf(v.w);
        *(us4*)&zf[((size_t)(n0 + ww)) * 256 + u * 4] = bv;
    }
}

// ---- full-K screen GEMM v4: 3-buffer ring + counted vmcnt across raw s_barrier (T4) ----
// grid 512 = 128 bm x 4 jg. Block: 4 waves = 4 row-groups, 256 rows x 2048 j.
// Per tile (32 j): wave does 64 rows: 8 ds_read_b128, 64 MFMA, 4 gload_lds prefetch.
__global__ __launch_bounds__(256) void k_screen3(const u16* __restrict__ zf,
                                                 const u16* __restrict__ cbh,
                                                 u16* __restrict__ pmaxT) {
    __shared__ u16 Bs[3][32 * 256];   // 3 x 16 KB ring
    const int t = threadIdx.x;
    const int wid = t >> 6, lane = t & 63;
    const int lr = lane & 15, lg = lane >> 4;
    const int bm = blockIdx.x >> 2;
    const int jg = blockIdx.x & 3;            // 4 j-groups of 2048
    const int wrow = bm * 256 + wid * 64;

    // A fragments: rows wrow + m*16 + lr, full K, straight from zf (one-time)
    short8 a[4][8];
    #pragma unroll
    for (int m = 0; m < 4; ++m) {
        const u16* zp = zf + (size_t)(wrow + m * 16 + lr) * 256 + lg * 8;
        #pragma unroll
        for (int ks = 0; ks < 8; ++ks)
            a[m][ks] = *(const short8*)&zp[ks * 32];
    }

    // staging source offsets (u16 units; row/unit XOR pre-swizzle, rule 21)
    int soff[4];
    #pragma unroll
    for (int s = 0; s < 4; ++s) {
        int c = s * 4 + wid;                  // instr 0..15, 1KB each
        int row = c * 2 + (lane >> 5);        // rows 0..31 of the 32-j tile
        int ug = (lane & 31) ^ (row & 7);
        soff[s] = row * 256 + ug * 8;
    }

    // b-frag LDS read addresses (swizzled), loop-invariant per lane
    const int rowb0 = lr;
    const int rowb1 = 16 + lr;
    int baddr0[8], baddr1[8];
    #pragma unroll
    for (int ks = 0; ks < 8; ++ks) {
        baddr0[ks] = rowb0 * 256 + (((ks * 4 + lg) ^ (rowb0 & 7)) * 8);
        baddr1[ks] = rowb1 * 256 + (((ks * 4 + lg) ^ (rowb1 & 7)) * 8);
    }

    auto stage = [&](int buf, int tile) {
        const u16* base = cbh + (size_t)(jg * 2048 + tile * 32) * 256;
        #pragma unroll
        for (int s = 0; s < 4; ++s)
            gload_lds16(base + soff[s], &Bs[buf][(s * 4 + wid) * 512]);
    };

    stage(0, 0);
    stage(1, 1);
    asm volatile("s_waitcnt vmcnt(4)" ::: "memory");   // tile 0 ready; tile 1 in flight
    __builtin_amdgcn_s_barrier();

    int cur = 0;
    for (int tile = 0; tile < 64; ++tile) {
        int nxt = cur + 2; if (nxt >= 3) nxt -= 3;
        if (tile < 62) stage(nxt, tile + 2);           // safe: barrier closed compute(tile-1)

        const u16* bsc = &Bs[cur][0];
        f32x4 acc[4][2] = {};
        #pragma unroll
        for (int ks = 0; ks < 8; ++ks) {
            short8 b0 = *(const short8*)&bsc[baddr0[ks]];
            short8 b1 = *(const short8*)&bsc[baddr1[ks]];
            #pragma unroll
            for (int m = 0; m < 4; ++m) {
                acc[m][0] = __builtin_amdgcn_mfma_f32_16x16x32_bf16(a[m][ks], b0, acc[m][0], 0, 0, 0);
                acc[m][1] = __builtin_amdgcn_mfma_f32_16x16x32_bf16(a[m][ks], b1, acc[m][1], 0, 0, 0);
            }
        }
        // epilogue: chunk = this tile's 32 j; DPP + v_pk_max_u16 reduce (VALU only)
        int chunk = jg * 64 + tile;
        #pragma unroll
        for (int m = 0; m < 4; ++m) {
            unsigned e01 = (unsigned)enc16ub(fmaxf(acc[m][0][0], acc[m][1][0]))
                         | ((unsigned)enc16ub(fmaxf(acc[m][0][1], acc[m][1][1])) << 16);
            unsigned e23 = (unsigned)enc16ub(fmaxf(acc[m][0][2], acc[m][1][2]))
                         | ((unsigned)enc16ub(fmaxf(acc[m][0][3], acc[m][1][3])) << 16);
            e01 = pkmaxu(e01, dpprorU<1>(e01));  e23 = pkmaxu(e23, dpprorU<1>(e23));
            e01 = pkmaxu(e01, dpprorU<2>(e01));  e23 = pkmaxu(e23, dpprorU<2>(e23));
            e01 = pkmaxu(e01, dpprorU<4>(e01));  e23 = pkmaxu(e23, dpprorU<4>(e23));
            e01 = pkmaxu(e01, dpprorU<8>(e01));  e23 = pkmaxu(e23, dpprorU<8>(e23));
            if (lr == 0) {
                us4 pack;
                pack.x = (u16)(e01 & 0xFFFFu); pack.y = (u16)(e01 >> 16);
                pack.z = (u16)(e23 & 0xFFFFu); pack.w = (u16)(e23 >> 16);
                *(us4*)&pmaxT[(size_t)chunk * NROWS + wrow + m * 16 + lg * 4] = pack;
            }
        }

        if (tile == 63) break;
        if (tile < 62) {
            asm volatile("s_waitcnt vmcnt(4)" ::: "memory");   // tile+1 ready; tile+2 stays in flight
        } else {
            asm volatile("s_waitcnt vmcnt(0)" ::: "memory");   // drain tail
        }
        __builtin_amdgcn_s_barrier();
        cur = cur + 1; if (cur >= 3) cur -= 3;
    }
}

// ---- rowmax + flag chunks >= thr; per-block LDS histogram kills hot-chunk atomic chains ----
__global__ __launch_bounds__(256) void k_flag(const u16* __restrict__ pmaxT,
                                              int* __restrict__ chunkcnt,     // stride 16 (pad)
                                              int* __restrict__ chunkrows,
                                              int* __restrict__ ovcnt,
                                              unsigned* __restrict__ ovlist) {
    __shared__ int lcnt[256];
    __shared__ int lslot[256];
    __shared__ int lbase[256];
    const int t = threadIdx.x;
    const int row = blockIdx.x * 256 + t;   // 128 blocks
    lcnt[t] = 0;
    lslot[t] = 0;

    float rm = -3.0e38f;
    for (int c = 0; c < NCHUNK; ++c)
        rm = fmaxf(rm, fdec((unsigned)pmaxT[(size_t)c * NROWS + row] << 16));
    const float thr = rm - MARGIN;

    u64 fl[4] = {0, 0, 0, 0};
    __syncthreads();
    for (int c = 0; c < NCHUNK; ++c) {
        float f = fdec((unsigned)pmaxT[(size_t)c * NROWS + row] << 16);
        if (f >= thr) {
            fl[c >> 6] |= 1ull << (c & 63);
            atomicAdd(&lcnt[c], 1);
        }
    }
    __syncthreads();
    {
        int myc = lcnt[t];
        lbase[t] = myc > 0 ? atomicAdd(&chunkcnt[t * 16], myc) : 0;
    }
    __syncthreads();
    for (int c = 0; c < NCHUNK; ++c) {
        if ((fl[c >> 6] >> (c & 63)) & 1) {
            int loc = atomicAdd(&lslot[c], 1);
            int slot = lbase[c] + loc;
            if (slot < MAXPER) {
                chunkrows[c * MAXPER + slot] = row;
            } else {
                int op = atomicAdd(ovcnt, 1);
                if (op < OVCAP) ovlist[op] = (unsigned)(row * NCHUNK + c);
            }
        }
    }
}

// ---- refine by chunk: stage 32 codes of cbf in LDS once, reuse across bucket rows ----
__global__ __launch_bounds__(256) void k_refine_bychunk(const float* __restrict__ zrow,
                                                        const float* __restrict__ cbf,
                                                        const float* __restrict__ Arow,
                                                        const int* __restrict__ chunkcnt,
                                                        const int* __restrict__ chunkrows,
                                                        u64* __restrict__ rowbest) {
    const int c = blockIdx.x;                    // chunk 0..255
    int cnt = chunkcnt[c * 16];
    if (cnt > MAXPER) cnt = MAXPER;
    if (cnt == 0) return;
    __shared__ float cl[32][260];                // +4 pad: conflict-free b128 column reads
    const int t = threadIdx.x;
    for (int u = t; u < 32 * 64; u += 256) {
        int code = u >> 6, kq = u & 63;
        *(float4*)&cl[code][kq * 4] = *(const float4*)&cbf[(size_t)(c * 32 + code) * 256 + kq * 4];
    }
    __syncthreads();
    const int wid = t >> 6, lane = t & 63;
    const int rsub = lane >> 4, lq = lane & 15;

    for (int i0 = blockIdx.y * 16 + wid * 4; i0 < cnt; i0 += 64) {
        int i = i0 + rsub;
        bool valid = i < cnt;
        int row = chunkrows[c * MAXPER + (valid ? i : 0)];
        const float* zp = zrow + (size_t)row * 256;
        float Ai = Arow[row];
        float C0 = 0.0f, C1 = 0.0f;
        #pragma unroll 8
        for (int kq = 0; kq < 64; ++kq) {
            float4 zv = *(const float4*)&zp[kq * 4];          // 16-lane broadcast
            float4 c0 = *(const float4*)&cl[lq][kq * 4];
            float4 c1 = *(const float4*)&cl[lq + 16][kq * 4];
            C0 = __builtin_fmaf(zv.x, c0.x, C0); C1 = __builtin_fmaf(zv.x, c1.x, C1);
            C0 = __builtin_fmaf(zv.y, c0.y, C0); C1 = __builtin_fmaf(zv.y, c1.y, C1);
            C0 = __builtin_fmaf(zv.z, c0.z, C0); C1 = __builtin_fmaf(zv.z, c1.z, C1);
            C0 = __builtin_fmaf(zv.w, c0.w, C0); C1 = __builtin_fmaf(zv.w, c1.w, C1);
        }
        float d0 = Ai - (C0 + C0);
        float d1 = Ai - (C1 + C1);
        int j0 = c * 32 + lq, j1 = j0 + 16;
        u64 k0 = ((u64)__float_as_uint(d0) << 32) | (unsigned)j0;
        u64 k1 = ((u64)__float_as_uint(d1) << 32) | (unsigned)j1;
        u64 key = k0 < k1 ? k0 : k1;
        if (!valid) key = ~0ull;
        #pragma unroll
        for (int mk = 1; mk < 16; mk <<= 1) {
            u64 o = __shfl_xor(key, mk, 64);
            if (o < key) key = o;
        }
        if (lq == 0 && valid) atomicMin(&rowbest[row], key);
    }
}

// ---- overflow refine (exact; expected never taken at MAXPER=8192) ----
__global__ __launch_bounds__(256) void k_refine_ov(const float* __restrict__ zrow,
                                                   const float* __restrict__ cbf,
                                                   const float* __restrict__ Arow,
                                                   const int* __restrict__ ovcnt,
                                                   const unsigned* __restrict__ ovlist,
                                                   u64* __restrict__ rowbest) {
    int total = *ovcnt;
    if (total > OVCAP) total = OVCAP;
    for (int p = blockIdx.x * 256 + threadIdx.x; p < total; p += gridDim.x * 256) {
        unsigned e = ovlist[p];
        int row = e / NCHUNK, chunk = e % NCHUNK;
        const float* zp = zrow + (size_t)row * 256;
        float Ai = Arow[row];
        u64 best = ~0ull;
        for (int q = 0; q < 32; ++q) {
            int j = chunk * 32 + q;
            float d = chain_d(zp, cbf + (size_t)j * 256, Ai);
            u64 key = ((u64)__float_as_uint(d) << 32) | (unsigned)j;
            if (key < best) best = key;
        }
        atomicMin(&rowbest[row], best);
    }
}

// ---- emit indices (never-taken exact full-scan fallback) ----
__global__ __launch_bounds__(256) void k_idx(const u64* __restrict__ rowbest,
                                             const float* __restrict__ zrow,
                                             const float* __restrict__ cbf,
                                             const float* __restrict__ Arow,
                                             int* __restrict__ idxw,
                                             float* __restrict__ idxf) {
    int row = blockIdx.x * 256 + threadIdx.x;   // 128 blocks
    u64 k = rowbest[row];
    int j;
    if (k != ~0ull) {
        j = (int)(k & 0xffffffffu);
    } else {
        u64 best = ~0ull;
        for (int jj = 0; jj < NE; ++jj) {
            float d = chain_d(zrow + (size_t)row * 256, cbf + (size_t)jj * 256, Arow[row]);
            u64 key = ((u64)__float_as_uint(d) << 32) | (unsigned)jj;
            if (key < best) best = key;
        }
        j = (int)(best & 0xffffffffu);
    }
    idxw[row] = j;
    idxf[row] = (float)j;
}

// ---- zq gather + fused MSE: 32 rows/block -> full 128B line writes per thread ----
__global__ __launch_bounds__(256) void k_zq_mse(const float* __restrict__ zrow,
                                                const float* __restrict__ cbf,
                                                const int* __restrict__ idxw,
                                                float* __restrict__ zq,
                                                double* __restrict__ blocksum) {
    const int t = threadIdx.x;
    const int n0 = blockIdx.x * 32;             // 1024 blocks
    double loc = 0.0;
    #pragma unroll 4
    for (int i = 0; i < 32; ++i) {
        int n = n0 + i;
        int j = idxw[n];                               // wave-uniform
        float q = cbf[(size_t)j * 256 + t];            // coalesced 1KB
        float zv = zrow[(size_t)n * 256 + t];          // coalesced 1KB (bit-copy of z)
        int b = n >> 10, h = (n >> 5) & 31, w = n & 31;
        zq[(((size_t)b * 256 + t) * 32 + h) * 32 + w] = q;   // thread fills its full 128B line
        double d = (double)q - (double)zv;
        loc += d * d;
    }
    #pragma unroll
    for (int mk = 1; mk < 64; mk <<= 1) loc += __shfl_xor(loc, mk, 64);
    __shared__ double wsum[4];
    int lane = t & 63, wid = t >> 6;
    if (lane == 0) wsum[wid] = loc;
    __syncthreads();
    if (t == 0) blocksum[blockIdx.x] = wsum[0] + wsum[1] + wsum[2] + wsum[3];
}

// ---- finalize scalars (sums 1024 block partials) ----
__global__ __launch_bounds__(256) void k_final(const double* __restrict__ blocksum,
                                               float* __restrict__ outs) {
    __shared__ double sh[4];
    int t = threadIdx.x;
    double s = 0.0;
    for (int i = t; i < 1024; i += 256) s += blocksum[i];
    #pragma unroll
    for (int mk = 1; mk < 64; mk <<= 1) s += __shfl_xor(s, mk, 64);
    int lane = t & 63, wid = t >> 6;
    if (lane == 0) sh[wid] = s;
    __syncthreads();
    if (t == 0) {
        double mse = (sh[0] + sh[1] + sh[2] + sh[3]) / (double)(32.0 * 256.0 * 32.0 * 32.0);
        outs[0] = (float)(1.25 * mse);   // loss
        outs[1] = (float)(0.25 * mse);   // commitment_loss
        outs[2] = (float)mse;            // codebook_loss
    }
}

extern "C" void kernel_launch(void* const* d_in, const int* in_sizes, int n_in,
                              void* d_out, int out_size, void* d_ws, size_t ws_size,
                              hipStream_t stream) {
    const float* z    = (const float*)d_in[0];
    const float* emb  = (const float*)d_in[1];
    const float* proj = (const float*)d_in[2];
    float* out = (float*)d_out;

    char* ws = (char*)d_ws;
    size_t o = 0;
    float*    cbf       = (float*)   (ws + o); o += (size_t)NE * 256 * 4;        // 8 MB
    u16*      cbh       = (u16*)     (ws + o); o += (size_t)NE * 256 * 2;        // 4 MB
    float*    zrow      = (float*)   (ws + o); o += (size_t)NROWS * 256 * 4;     // 32 MB
    u16*      zf        = (u16*)     (ws + o); o += (size_t)NROWS * 256 * 2;     // 16 MB
    float*    Arow      = (float*)   (ws + o); o += (size_t)NROWS * 4;
    u16*      pmaxT     = (u16*)     (ws + o); o += (size_t)NCHUNK * NROWS * 2;  // 16 MB
    int*      chunkcnt  = (int*)     (ws + o); o += (size_t)NCHUNK * 16 * 4;     // padded
    int*      chunkrows = (int*)     (ws + o); o += (size_t)NCHUNK * MAXPER * 4; // 8 MB
    int*      ovcnt     = (int*)     (ws + o); o += 64;
    unsigned* ovlist    = (unsigned*)(ws + o); o += (size_t)OVCAP * 4;           // 1 MB
    u64*      rowbest   = (u64*)     (ws + o); o += (size_t)NROWS * 8;           // 256 KB
    int*      idxw      = (int*)     (ws + o); o += (size_t)NROWS * 4;
    double*   blocksum  = (double*)  (ws + o); o += 1024 * 8;
    if (o > ws_size) return;

    hipMemsetAsync(chunkcnt, 0, (size_t)NCHUNK * 16 * 4, stream);
    hipMemsetAsync(ovcnt, 0, 64, stream);
    hipMemsetAsync(rowbest, 0xFF, (size_t)NROWS * 8, stream);     // ~0ull

    k_cbchain<<<dim3(1024), dim3(256), 0, stream>>>(emb, proj, cbf, cbh);
    k_zrow<<<dim3(1024), dim3(256), 0, stream>>>(z, zrow, zf, Arow);
    k_screen3<<<dim3(512), dim3(256), 0, stream>>>(zf, cbh, pmaxT);
    k_flag<<<dim3(NROWS / 256), dim3(256), 0, stream>>>(pmaxT, chunkcnt, chunkrows, ovcnt, ovlist);
    k_refine_bychunk<<<dim3(NCHUNK, 4), dim3(256), 0, stream>>>(zrow, cbf, Arow, chunkcnt, chunkrows, rowbest);
    k_refine_ov<<<dim3(64), dim3(256), 0, stream>>>(zrow, cbf, Arow, ovcnt, ovlist, rowbest);
    k_idx<<<dim3(NROWS / 256), dim3(256), 0, stream>>>(rowbest, zrow, cbf, Arow, idxw, out + 8388611);
    k_zq_mse<<<dim3(1024), dim3(256), 0, stream>>>(zrow, cbf, idxw, out, blocksum);
    k_final<<<dim3(1), dim3(256), 0, stream>>>(blocksum, out + 8388608);
}